// Round 7
// baseline (168.683 us; speedup 1.0000x reference)
//
#include <hip/hip_runtime.h>
#include <math.h>

static __device__ __forceinline__ float lrelu(float x){ return x > 0.f ? x : 0.01f * x; }

// ---- workspace layout (float offsets) ----
#define OFF_XE    196608
#define OFF_XA    294912
#define OFF_QKVE  393216
#define OFF_QKVA  688128
#define OFF_AOP   983040    // 4 splits * 768*128
#define OFF_DEN   1376256   // 4 splits * 768*4
#define OFF_AOA   1388544   // 15*96*128
#define OFF_QVE   1572864
#define OFF_QVA   1573632
#define WS_FLOATS 1575072

// ---- output layout (fp32 elems) ----
#define OUT_POL 0
#define OUT_QV  24576
#define OUT_EO  25344

#define SCALE_ATTN 0.17677669529663689f  // 1/sqrt(32)

// Phase fence: keeps the compiler from hoisting later phases' weight loads
// across __syncthreads (r17 lesson: VGPR 256 + spill).
#define PHASE_FENCE() __builtin_amdgcn_sched_barrier(0)

// r21 cdot8 (PROVEN WIN): cluster-coalesced weight dot. c=t>>2, o=(t&3)*4:
// each 4-lane cluster owns one output column and reads 16 CONSECUTIVE floats
// of W-row c per chunk -> 16 cache lines per wave-load vs 64 for the
// per-lane-row layout. r21 measured: front 40.9 -> <40.5 (total -8us).
// These phases are L1-line-transaction bound (TLP/balance/conflict fixes
// all null in r19/r20).
static __device__ __forceinline__ void cdot8(
    const float* __restrict__ wrow, int o,   // o = (t&3)*4
    const float* __restrict__ x0, const float* __restrict__ x1,
    const float* __restrict__ x2, const float* __restrict__ x3,
    float* __restrict__ accs)
{
  float4 wf[8];
  #pragma unroll
  for (int ch = 0; ch < 8; ++ch)
    wf[ch] = *(const float4*)&wrow[ch * 16 + o];
  #pragma unroll
  for (int r = 0; r < 4; ++r) {
    const float* xr = (r == 0) ? x0 : (r == 1) ? x1 : (r == 2) ? x2 : x3;
    float ax = 0.f, ay = 0.f, az = 0.f, aw = 0.f;
    #pragma unroll
    for (int ch = 0; ch < 8; ++ch) {
      float4 x = *(const float4*)&xr[ch * 16 + o];
      ax = fmaf(x.x, wf[ch].x, ax); ay = fmaf(x.y, wf[ch].y, ay);
      az = fmaf(x.z, wf[ch].z, az); aw = fmaf(x.w, wf[ch].w, aw);
    }
    accs[r] += (ax + ay) + (az + aw);
  }
}

// 2-chunk (32-float) variant for K=160's tail region.
static __device__ __forceinline__ void cdot2(
    const float* __restrict__ wrow, int o,
    const float* __restrict__ x0, const float* __restrict__ x1,
    const float* __restrict__ x2, const float* __restrict__ x3,
    float* __restrict__ accs)
{
  float4 wf[2];
  #pragma unroll
  for (int ch = 0; ch < 2; ++ch)
    wf[ch] = *(const float4*)&wrow[ch * 16 + o];
  #pragma unroll
  for (int r = 0; r < 4; ++r) {
    const float* xr = (r == 0) ? x0 : (r == 1) ? x1 : (r == 2) ? x2 : x3;
    float ax = 0.f, ay = 0.f, az = 0.f, aw = 0.f;
    #pragma unroll
    for (int ch = 0; ch < 2; ++ch) {
      float4 x = *(const float4*)&xr[ch * 16 + o];
      ax = fmaf(x.x, wf[ch].x, ax); ay = fmaf(x.y, wf[ch].y, ay);
      az = fmaf(x.z, wf[ch].z, az); aw = fmaf(x.w, wf[ch].w, aw);
    }
    accs[r] += (ax + ay) + (az + aw);
  }
}

// ================================================================
// K12ws r21 (unchanged): weight-stationary front, 4 rows/block, grid 384,
// 512 threads, cluster-coalesced weight access.
// Blocks 0..191   (E): obs -> eo -> x_e -> qkv_e
// Blocks 192..383 (A): obs -> L1 -> L2 -> L3/pol -> ea -> x_a -> qkv_a
// ================================================================
__global__ __launch_bounds__(512, 1) void k12ws_front(
    const float* __restrict__ obs,
    const float* __restrict__ aw1, const float* __restrict__ ab1,
    const float* __restrict__ aw2, const float* __restrict__ ab2,
    const float* __restrict__ aw3, const float* __restrict__ ab3,
    const float* __restrict__ eow, const float* __restrict__ eob,
    const float* __restrict__ eaw, const float* __restrict__ eab,
    const float* __restrict__ riw, const float* __restrict__ rib,
    const float* __restrict__ miw, const float* __restrict__ mib,
    float* __restrict__ out, float* __restrict__ ws)
{
  __shared__ float sA[4][256];   // A: h1, then ea in [0..128)  | E: eo
  __shared__ float sB[4][160];   // A: [obs | pol]              | E: obs
  __shared__ float sC[4][128];   // A: h2, then x_a             | E: x_e
  const int t  = threadIdx.x;
  const int bx = blockIdx.x;
  const bool isE = (bx < 192);
  const int r0 = (isE ? bx : bx - 192) * 4;

  const int c  = t >> 2;        // out-col 0..127 (one per 4-lane cluster)
  const int o  = (t & 3) * 4;   // 4-float k-slice within each 16-float chunk
  const bool q0 = (t & 3) == 0;

  { // stage obs: 512 floats, 512 threads (coalesced)
    int ri = t >> 7, k = t & 127;
    sB[ri][k] = obs[(r0 + ri) * 128 + k];
  }
  __syncthreads();
  PHASE_FENCE();

  if (isE) {
    { // ---- eo ----
      float accs[4] = {0.f, 0.f, 0.f, 0.f};
      cdot8(eow + (size_t)c * 128, o,
            sB[0], sB[1], sB[2], sB[3], accs);
      const float bias = eob[c];
      #pragma unroll
      for (int r = 0; r < 4; ++r) {
        float acc = accs[r];
        acc += __shfl_xor(acc, 1);
        acc += __shfl_xor(acc, 2);
        if (q0) {
          float v = acc + bias;
          sA[r][c] = v;
          out[OUT_EO + (r0 + r) * 128 + c] = v;
        }
      }
    }
    __syncthreads();
    PHASE_FENCE();
    { // ---- x_e ----
      float accs[4] = {0.f, 0.f, 0.f, 0.f};
      cdot8(riw + (size_t)c * 128, o,
            sA[0], sA[1], sA[2], sA[3], accs);
      const float bias = rib[c];
      #pragma unroll
      for (int r = 0; r < 4; ++r) {
        float acc = accs[r];
        acc += __shfl_xor(acc, 1);
        acc += __shfl_xor(acc, 2);
        if (q0) {
          float v = fmaxf(acc + bias, 0.f);
          sC[r][c] = v;
          ws[OFF_XE + (r0 + r) * 128 + c] = v;
        }
      }
    }
    __syncthreads();
    PHASE_FENCE();
    // ---- qkv_e (3 col-groups) ----
    #pragma unroll 1
    for (int g = 0; g < 3; ++g) {
      float accs[4] = {0.f, 0.f, 0.f, 0.f};
      cdot8(miw + (size_t)(g * 128 + c) * 128, o,
            sC[0], sC[1], sC[2], sC[3], accs);
      const float bias = mib[g * 128 + c];
      #pragma unroll
      for (int r = 0; r < 4; ++r) {
        float acc = accs[r];
        acc += __shfl_xor(acc, 1);
        acc += __shfl_xor(acc, 2);
        if (q0)
          ws[OFF_QKVE + (size_t)(r0 + r) * 384 + g * 128 + c] = acc + bias;
      }
    }
  } else {
    // ---- L1 (2 col-groups) ----
    #pragma unroll 1
    for (int g = 0; g < 2; ++g) {
      float accs[4] = {0.f, 0.f, 0.f, 0.f};
      cdot8(aw1 + (size_t)(g * 128 + c) * 128, o,
            sB[0], sB[1], sB[2], sB[3], accs);
      const float bias = ab1[g * 128 + c];
      #pragma unroll
      for (int r = 0; r < 4; ++r) {
        float acc = accs[r];
        acc += __shfl_xor(acc, 1);
        acc += __shfl_xor(acc, 2);
        if (q0) sA[r][g * 128 + c] = lrelu(acc + bias);
      }
    }
    __syncthreads();
    PHASE_FENCE();
    { // ---- L2 (K=256: two 128-halves, serial cdot8 pair) ----
      float accs[4] = {0.f, 0.f, 0.f, 0.f};
      cdot8(aw2 + (size_t)c * 256, o,
            &sA[0][0], &sA[1][0], &sA[2][0], &sA[3][0], accs);
      cdot8(aw2 + (size_t)c * 256 + 128, o,
            &sA[0][128], &sA[1][128], &sA[2][128], &sA[3][128], accs);
      const float bias = ab2[c];
      #pragma unroll
      for (int r = 0; r < 4; ++r) {
        float acc = accs[r];
        acc += __shfl_xor(acc, 1);
        acc += __shfl_xor(acc, 2);
        if (q0) sC[r][c] = lrelu(acc + bias);
      }
    }
    __syncthreads();
    PHASE_FENCE();
    // ---- L3 + GELU (threads 0..127: 32 cols x 4 q) ----
    if (t < 128) {
      const int c2 = t >> 2;
      float accs[4] = {0.f, 0.f, 0.f, 0.f};
      cdot8(aw3 + (size_t)c2 * 128, o,
            sC[0], sC[1], sC[2], sC[3], accs);
      const float bias = ab3[c2];
      #pragma unroll
      for (int r = 0; r < 4; ++r) {
        float acc = accs[r];
        acc += __shfl_xor(acc, 1);
        acc += __shfl_xor(acc, 2);
        if (q0) {
          float a = acc + bias;
          float g = 0.5f * a * (1.f + erff(a * 0.70710678118654752f));
          sB[r][128 + c2] = g;
          out[OUT_POL + (r0 + r) * 32 + c2] = g;
        }
      }
    }
    __syncthreads();
    PHASE_FENCE();
    { // ---- ea (K=160: 8 chunks over obs + 2 chunks over pol) ----
      float accs[4] = {0.f, 0.f, 0.f, 0.f};
      const float* wb = eaw + (size_t)c * 160;
      cdot8(wb, o, sB[0], sB[1], sB[2], sB[3], accs);
      cdot2(wb + 128, o,
            &sB[0][128], &sB[1][128], &sB[2][128], &sB[3][128], accs);
      const float bias = eab[c];
      #pragma unroll
      for (int r = 0; r < 4; ++r) {
        float acc = accs[r];
        acc += __shfl_xor(acc, 1);
        acc += __shfl_xor(acc, 2);
        if (q0) sA[r][c] = acc + bias;
      }
    }
    __syncthreads();
    PHASE_FENCE();
    { // ---- x_a ----
      float accs[4] = {0.f, 0.f, 0.f, 0.f};
      cdot8(riw + (size_t)c * 128, o,
            sA[0], sA[1], sA[2], sA[3], accs);
      const float bias = rib[c];
      #pragma unroll
      for (int r = 0; r < 4; ++r) {
        float acc = accs[r];
        acc += __shfl_xor(acc, 1);
        acc += __shfl_xor(acc, 2);
        if (q0) {
          float v = fmaxf(acc + bias, 0.f);
          sC[r][c] = v;
          ws[OFF_XA + (r0 + r) * 128 + c] = v;
        }
      }
    }
    __syncthreads();
    PHASE_FENCE();
    // ---- qkv_a (3 col-groups) ----
    #pragma unroll 1
    for (int g = 0; g < 3; ++g) {
      float accs[4] = {0.f, 0.f, 0.f, 0.f};
      cdot8(miw + (size_t)(g * 128 + c) * 128, o,
            sC[0], sC[1], sC[2], sC[3], accs);
      const float bias = mib[g * 128 + c];
      #pragma unroll
      for (int r = 0; r < 4; ++r) {
        float acc = accs[r];
        acc += __shfl_xor(acc, 1);
        acc += __shfl_xor(acc, 2);
        if (q0)
          ws[OFF_QKVA + (size_t)(r0 + r) * 384 + g * 128 + c] = acc + bias;
      }
    }
  }
}

// ================================================================
// K356: fused attention (r15 exact).
// ================================================================
__global__ __launch_bounds__(256) void k356_attn(float* __restrict__ ws)
{
  __shared__ __align__(16) union {
    struct { float Qs[16 * 36]; float KsT[32 * 68]; float VsT[32 * 68]; float Ss[16 * 68]; } e;
    struct { float Qb[48 * 33]; float Ka[96 * 33]; float Va[96 * 36]; float Ss[48 * 97]; float rinv[48]; } a;
  } su;
  const int t  = threadIdx.x;
  const int bx = blockIdx.x;

  if (bx < 768) {
    const int l0 = (bx % 48) * 16, h = (bx / 48) & 3, sp = bx / 192;
    const float* qkve = ws + OFF_QKVE;

    for (int f = t; f < 512; f += 256)
      su.e.Qs[(f >> 5) * 36 + (f & 31)] = qkve[(size_t)(l0 + (f >> 5)) * 384 + h * 32 + (f & 31)];
    __syncthreads();

    const int l = t >> 4, j = t & 15, c0 = j * 4;
    float q[32];
    #pragma unroll
    for (int dd = 0; dd < 8; ++dd) {
      float4 qq = *(const float4*)&su.e.Qs[l * 36 + dd * 4];
      q[dd*4+0] = qq.x; q[dd*4+1] = qq.y; q[dd*4+2] = qq.z; q[dd*4+3] = qq.w;
    }
    float o0 = 0.f, o1 = 0.f, dsum = 0.f;

    for (int mt = sp * 3; mt < sp * 3 + 3; ++mt) {
      const int m0 = mt * 64;
      __syncthreads();
      for (int f = t; f < 2048; f += 256) {
        int i = f >> 5, d = f & 31;
        const float* src = qkve + (size_t)(m0 + i) * 384 + h * 32 + d;
        su.e.KsT[d * 68 + i] = src[128];
        su.e.VsT[d * 68 + i] = src[256];
      }
      __syncthreads();

      float s0 = 0.f, s1 = 0.f, s2 = 0.f, s3 = 0.f;
      #pragma unroll
      for (int d = 0; d < 32; ++d) {
        float4 kk = *(const float4*)&su.e.KsT[d * 68 + c0];
        s0 = fmaf(q[d], kk.x, s0); s1 = fmaf(q[d], kk.y, s1);
        s2 = fmaf(q[d], kk.z, s2); s3 = fmaf(q[d], kk.w, s3);
      }
      s0 = expf(s0 * SCALE_ATTN); s1 = expf(s1 * SCALE_ATTN);
      s2 = expf(s2 * SCALE_ATTN); s3 = expf(s3 * SCALE_ATTN);
      float4 sv; sv.x = s0; sv.y = s1; sv.z = s2; sv.w = s3;
      *(float4*)&su.e.Ss[l * 68 + c0] = sv;
      float psum = (s0 + s1) + (s2 + s3);
      psum += __shfl_xor(psum, 1); psum += __shfl_xor(psum, 2);
      psum += __shfl_xor(psum, 4); psum += __shfl_xor(psum, 8);
      dsum += psum;

      float t0x=0.f,t0y=0.f,t0z=0.f,t0w=0.f, t1x=0.f,t1y=0.f,t1z=0.f,t1w=0.f;
      #pragma unroll
      for (int k4 = 0; k4 < 16; ++k4) {
        float4 p  = *(const float4*)&su.e.Ss[l * 68 + k4 * 4];
        float4 va = *(const float4*)&su.e.VsT[j * 68 + k4 * 4];
        float4 vb = *(const float4*)&su.e.VsT[(j + 16) * 68 + k4 * 4];
        t0x = fmaf(p.x, va.x, t0x); t0y = fmaf(p.y, va.y, t0y);
        t0z = fmaf(p.z, va.z, t0z); t0w = fmaf(p.w, va.w, t0w);
        t1x = fmaf(p.x, vb.x, t1x); t1y = fmaf(p.y, vb.y, t1y);
        t1z = fmaf(p.z, vb.z, t1z); t1w = fmaf(p.w, vb.w, t1w);
      }
      o0 += (t0x + t0y) + (t0z + t0w);
      o1 += (t1x + t1y) + (t1z + t1w);
    }

    float* aop = ws + OFF_AOP + (size_t)sp * 98304;
    aop[(size_t)(l0 + l) * 128 + h * 32 + j]      = o0;
    aop[(size_t)(l0 + l) * 128 + h * 32 + j + 16] = o1;
    if (j == 0) ws[OFF_DEN + sp * 3072 + (l0 + l) * 4 + h] = dsum;
  } else {
    const int z  = bx - 768;
    const int j1 = z >> 3;
    const int h  = (z & 7) >> 1, rb = z & 1;
    const int jj = j1 + 1;
    const float* qkva = ws + OFF_QKVA;

    for (int f = t; f < 3072; f += 256) {
      int ml = f >> 5, d = f & 31;
      int bp = ml >> 1, spar = ml & 1;
      int ag = spar ? jj : (jj - 1);
      const float* src = qkva + (size_t)(bp * 16 + ag) * 384 + h * 32 + d;
      su.a.Ka[ml * 33 + d] = src[128];
      su.a.Va[ml * 36 + d] = src[256];
    }
    for (int f = t; f < 1536; f += 256) {
      int ql = f >> 5, d = f & 31;
      int Lb = rb * 48 + ql;
      int b = Lb >> 1, s = Lb & 1;
      int ag = s ? jj : (jj - 1);
      su.a.Qb[ql * 33 + d] = qkva[(size_t)(b * 16 + ag) * 384 + h * 32 + d];
    }
    __syncthreads();

    {
      const int tl = (t >> 4) * 3, tm = (t & 15) * 6;
      float acc[3][6] = {{0.f}};
      #pragma unroll
      for (int d = 0; d < 32; ++d) {
        float qv[3], kv[6];
        #pragma unroll
        for (int r = 0; r < 3; ++r) qv[r] = su.a.Qb[(tl + r) * 33 + d];
        #pragma unroll
        for (int c = 0; c < 6; ++c) kv[c] = su.a.Ka[(tm + c) * 33 + d];
        #pragma unroll
        for (int r = 0; r < 3; ++r)
          #pragma unroll
          for (int c = 0; c < 6; ++c) acc[r][c] = fmaf(qv[r], kv[c], acc[r][c]);
      }
      const float wj = (float)jj, wnj = (float)(16 - jj);
      float rs[3] = {0.f, 0.f, 0.f};
      #pragma unroll
      for (int r = 0; r < 3; ++r)
        #pragma unroll
        for (int c = 0; c < 6; ++c) {
          float w = ((tm + c) & 1) ? wj : wnj;
          float p = w * expf(acc[r][c] * SCALE_ATTN);
          su.a.Ss[(tl + r) * 97 + tm + c] = p;
          rs[r] += p;
        }
      #pragma unroll
      for (int r = 0; r < 3; ++r) {
        rs[r] += __shfl_xor(rs[r], 1); rs[r] += __shfl_xor(rs[r], 2);
        rs[r] += __shfl_xor(rs[r], 4); rs[r] += __shfl_xor(rs[r], 8);
      }
      if ((t & 15) == 0) {
        su.a.rinv[tl + 0] = 1.f / rs[0];
        su.a.rinv[tl + 1] = 1.f / rs[1];
        su.a.rinv[tl + 2] = 1.f / rs[2];
      }
    }
    __syncthreads();

    if (t < 192) {
      const int l0 = (t >> 3) * 2, d0 = (t & 7) * 4;
      float a0x=0.f,a0y=0.f,a0z=0.f,a0w=0.f, a1x=0.f,a1y=0.f,a1z=0.f,a1w=0.f;
      for (int m = 0; m < 96; ++m) {
        float p0 = su.a.Ss[l0 * 97 + m], p1 = su.a.Ss[(l0 + 1) * 97 + m];
        float4 v = *(const float4*)&su.a.Va[m * 36 + d0];
        a0x = fmaf(p0, v.x, a0x); a0y = fmaf(p0, v.y, a0y);
        a0z = fmaf(p0, v.z, a0z); a0w = fmaf(p0, v.w, a0w);
        a1x = fmaf(p1, v.x, a1x); a1y = fmaf(p1, v.y, a1y);
        a1z = fmaf(p1, v.z, a1z); a1w = fmaf(p1, v.w, a1w);
      }
      const float s0 = su.a.rinv[l0], s1 = su.a.rinv[l0 + 1];
      float* ao = ws + OFF_AOA + (size_t)(j1 * 96 + rb * 48 + l0) * 128 + h * 32 + d0;
      float4 o0; o0.x = a0x * s0; o0.y = a0y * s0; o0.z = a0z * s0; o0.w = a0w * s0;
      float4 o1; o1.x = a1x * s1; o1.y = a1y * s1; o1.z = a1z * s1; o1.w = a1w * s1;
      *(float4*)ao = o0;
      *(float4*)(ao + 128) = o1;
    }
  }
}

// ================================================================
// K7ab r22: merged epilogue, cluster-coalesced like the front.
// 512 threads; c = t>>2 (one col per 4-lane cluster), o = (t&3)*4.
// Weight wave-loads: 16 lines instead of 64 (same pathology/fix as r21
// front). LDS x reads: 16-way broadcast, conflict-free. Reduce:
// shfl_xor(1)+(2); qv: per-cluster mask then full-wave reduce into
// qpart[ri][wave].
// ================================================================
__global__ __launch_bounds__(512, 1) void k7ab_epi(
    const float* __restrict__ mow, const float* __restrict__ mob,
    const float* __restrict__ roww, const float* __restrict__ robb,
    const float* __restrict__ qw,  const float* __restrict__ qb,
    float* __restrict__ ws)
{
  __shared__ float rows_in[8][132];
  __shared__ float res[8][132];
  __shared__ float t1s[8][132];
  __shared__ float qpart[8][8];
  const int t  = threadIdx.x;
  const int r0 = blockIdx.x * 8;

  for (int s = t; s < 1024; s += 512) {
    int ri = s >> 7, c = s & 127;
    int r = r0 + ri;
    float aoval, x1v;
    if (r < 768) {
      float num = ws[OFF_AOP + 0*98304 + (size_t)r*128 + c]
                + ws[OFF_AOP + 1*98304 + (size_t)r*128 + c]
                + ws[OFF_AOP + 2*98304 + (size_t)r*128 + c]
                + ws[OFF_AOP + 3*98304 + (size_t)r*128 + c];
      int hh = c >> 5;
      float den = ws[OFF_DEN + 0*3072 + r*4 + hh] + ws[OFF_DEN + 1*3072 + r*4 + hh]
                + ws[OFF_DEN + 2*3072 + r*4 + hh] + ws[OFF_DEN + 3*3072 + r*4 + hh];
      aoval = num / den;
      x1v = ws[OFF_XE + r*128 + c];
    } else {
      int rr = r - 768;
      aoval = ws[OFF_AOA + (size_t)rr*128 + c];
      int jx = rr / 96, l96 = rr % 96;
      int b = l96 >> 1, sa = l96 & 1;
      int ag = sa ? (jx + 1) : jx;
      x1v = ws[OFF_XA + (b*16 + ag)*128 + c];
    }
    rows_in[ri][c] = aoval;
    res[ri][c] = x1v;
  }

  const int c  = t >> 2;        // out-col 0..127
  const int o  = (t & 3) * 4;   // k-slice within 16-float chunk
  const bool q0 = (t & 3) == 0;
  __syncthreads();
  PHASE_FENCE();

  { // t1 phase — cluster-coalesced mow
    float accs[8] = {0.f,0.f,0.f,0.f,0.f,0.f,0.f,0.f};
    const float* wrow = mow + (size_t)c * 128;
    float4 wf[8];
    #pragma unroll
    for (int ch = 0; ch < 8; ++ch)
      wf[ch] = *(const float4*)&wrow[ch * 16 + o];
    #pragma unroll
    for (int ri = 0; ri < 8; ++ri) {
      const float* xr = rows_in[ri];
      float ax = 0.f, ay = 0.f, az = 0.f, aw = 0.f;
      #pragma unroll
      for (int ch = 0; ch < 8; ++ch) {
        float4 x = *(const float4*)&xr[ch * 16 + o];
        ax = fmaf(x.x, wf[ch].x, ax); ay = fmaf(x.y, wf[ch].y, ay);
        az = fmaf(x.z, wf[ch].z, az); aw = fmaf(x.w, wf[ch].w, aw);
      }
      accs[ri] = (ax + ay) + (az + aw);
    }
    const float bias = mob[c];
    #pragma unroll
    for (int ri = 0; ri < 8; ++ri) {
      float acc = accs[ri];
      acc += __shfl_xor(acc, 1);
      acc += __shfl_xor(acc, 2);
      if (q0) t1s[ri][c] = acc + bias + res[ri][c];
    }
  }
  __syncthreads();
  PHASE_FENCE();

  { // ctx + qv phase — cluster-coalesced roww
    float accs[8] = {0.f,0.f,0.f,0.f,0.f,0.f,0.f,0.f};
    const float* wrow = roww + (size_t)c * 128;
    float4 wf[8];
    #pragma unroll
    for (int ch = 0; ch < 8; ++ch)
      wf[ch] = *(const float4*)&wrow[ch * 16 + o];
    #pragma unroll
    for (int ri = 0; ri < 8; ++ri) {
      const float* xr = t1s[ri];
      float ax = 0.f, ay = 0.f, az = 0.f, aw = 0.f;
      #pragma unroll
      for (int ch = 0; ch < 8; ++ch) {
        float4 x = *(const float4*)&xr[ch * 16 + o];
        ax = fmaf(x.x, wf[ch].x, ax); ay = fmaf(x.y, wf[ch].y, ay);
        az = fmaf(x.z, wf[ch].z, az); aw = fmaf(x.w, wf[ch].w, aw);
      }
      accs[ri] = (ax + ay) + (az + aw);
    }
    const float bias = robb[c];
    const float qwc  = qw[c];
    #pragma unroll
    for (int ri = 0; ri < 8; ++ri) {
      float acc = accs[ri];
      acc += __shfl_xor(acc, 1);
      acc += __shfl_xor(acc, 2);
      float ctx = fmaxf(acc + bias, 0.f);
      float p = q0 ? qwc * ctx : 0.f;     // count each col once
      p += __shfl_xor(p, 1);  p += __shfl_xor(p, 2);  p += __shfl_xor(p, 4);
      p += __shfl_xor(p, 8);  p += __shfl_xor(p, 16); p += __shfl_xor(p, 32);
      if ((t & 63) == 0) qpart[ri][t >> 6] = p;
    }
  }
  __syncthreads();

  if (t < 8) {
    float qv = ((qpart[t][0] + qpart[t][1]) + (qpart[t][2] + qpart[t][3]))
             + ((qpart[t][4] + qpart[t][5]) + (qpart[t][6] + qpart[t][7])) + qb[0];
    int r = r0 + t;
    if (r < 768) ws[OFF_QVE + r] = qv;
    else         ws[OFF_QVA + (r - 768)] = qv;
  }
}

// ================================================================
// K8: q_values[b,i] = qv_e[b,i] + sum_j qv_a
// ================================================================
__global__ __launch_bounds__(256) void k8_final(const float* __restrict__ ws, float* __restrict__ out)
{
  const int idx = blockIdx.x * 256 + threadIdx.x;
  if (idx >= 768) return;
  const int b = idx >> 4, i = idx & 15;
  float acc = ws[OFF_QVE + idx];
  const float* qva = ws + OFF_QVA;
  #pragma unroll
  for (int j = 1; j <= 15; ++j) {
    int s = (i >= j) ? 0 : 1;
    acc += qva[(j - 1) * 96 + b * 2 + s];
  }
  out[OUT_QV + idx] = acc;
}

// ================================================================
extern "C" void kernel_launch(void* const* d_in, const int* in_sizes, int n_in,
                              void* d_out, int out_size, void* d_ws, size_t ws_size,
                              hipStream_t stream)
{
  (void)in_sizes; (void)n_in; (void)out_size;
  if (ws_size < (size_t)WS_FLOATS * 4) return;

  const float* obs = (const float*)d_in[0];
  const float* aw1 = (const float*)d_in[1];
  const float* ab1 = (const float*)d_in[2];
  const float* aw2 = (const float*)d_in[3];
  const float* ab2 = (const float*)d_in[4];
  const float* aw3 = (const float*)d_in[5];
  const float* ab3 = (const float*)d_in[6];
  const float* eow = (const float*)d_in[7];
  const float* eob = (const float*)d_in[8];
  const float* eaw = (const float*)d_in[9];
  const float* eab = (const float*)d_in[10];
  const float* riw = (const float*)d_in[11];
  const float* rib = (const float*)d_in[12];
  const float* roww= (const float*)d_in[13];
  const float* robb= (const float*)d_in[14];
  const float* miw = (const float*)d_in[15];
  const float* mib = (const float*)d_in[16];
  const float* mow = (const float*)d_in[17];
  const float* mob = (const float*)d_in[18];
  const float* qw  = (const float*)d_in[19];
  const float* qb  = (const float*)d_in[20];

  float* out = (float*)d_out;
  float* ws  = (float*)d_ws;

  k12ws_front<<<dim3(384), dim3(512), 0, stream>>>(obs, aw1, ab1, aw2, ab2, aw3, ab3,
                                                   eow, eob, eaw, eab, riw, rib, miw, mib,
                                                   out, ws);
  k356_attn<<<dim3(888), dim3(256), 0, stream>>>(ws);
  k7ab_epi<<<dim3(276), dim3(512), 0, stream>>>(mow, mob, roww, robb, qw, qb, ws);
  k8_final<<<dim3(3), dim3(256), 0, stream>>>(ws, out);
}

// Round 8
// 161.578 us; speedup vs baseline: 1.0440x; 1.0440x over previous
//
#include <hip/hip_runtime.h>
#include <math.h>

static __device__ __forceinline__ float lrelu(float x){ return x > 0.f ? x : 0.01f * x; }

// ---- workspace layout (float offsets) ----
#define OFF_XE    196608
#define OFF_XA    294912
#define OFF_QKVE  393216
#define OFF_QKVA  688128
#define OFF_AOP   983040    // 4 splits * 768*128
#define OFF_DEN   1376256   // 4 splits * 768*4
#define OFF_AOA   1388544   // 15*96*128
#define WS_FLOATS 1575072

// ---- output layout (fp32 elems) ----
#define OUT_POL 0
#define OUT_QV  24576
#define OUT_EO  25344

#define SCALE_ATTN 0.17677669529663689f  // 1/sqrt(32)

// Phase fence: keeps the compiler from hoisting later phases' weight loads
// across __syncthreads (r17 lesson: VGPR 256 + spill).
#define PHASE_FENCE() __builtin_amdgcn_sched_barrier(0)

// r21 cdot8 (PROVEN WIN): cluster-coalesced weight dot. c=t>>2, o=(t&3)*4:
// each 4-lane cluster owns one output column and reads 16 CONSECUTIVE floats
// of W-row c per chunk -> 16 cache lines per wave-load vs 64 for the
// per-lane-row layout (front 40.9 -> ~33, total -8us). These phases are
// L1-line-transaction bound (TLP/balance/conflict fixes all null r19/r20).
static __device__ __forceinline__ void cdot8(
    const float* __restrict__ wrow, int o,   // o = (t&3)*4
    const float* __restrict__ x0, const float* __restrict__ x1,
    const float* __restrict__ x2, const float* __restrict__ x3,
    float* __restrict__ accs)
{
  float4 wf[8];
  #pragma unroll
  for (int ch = 0; ch < 8; ++ch)
    wf[ch] = *(const float4*)&wrow[ch * 16 + o];
  #pragma unroll
  for (int r = 0; r < 4; ++r) {
    const float* xr = (r == 0) ? x0 : (r == 1) ? x1 : (r == 2) ? x2 : x3;
    float ax = 0.f, ay = 0.f, az = 0.f, aw = 0.f;
    #pragma unroll
    for (int ch = 0; ch < 8; ++ch) {
      float4 x = *(const float4*)&xr[ch * 16 + o];
      ax = fmaf(x.x, wf[ch].x, ax); ay = fmaf(x.y, wf[ch].y, ay);
      az = fmaf(x.z, wf[ch].z, az); aw = fmaf(x.w, wf[ch].w, aw);
    }
    accs[r] += (ax + ay) + (az + aw);
  }
}

// 2-chunk (32-float) variant for K=160's tail region.
static __device__ __forceinline__ void cdot2(
    const float* __restrict__ wrow, int o,
    const float* __restrict__ x0, const float* __restrict__ x1,
    const float* __restrict__ x2, const float* __restrict__ x3,
    float* __restrict__ accs)
{
  float4 wf[2];
  #pragma unroll
  for (int ch = 0; ch < 2; ++ch)
    wf[ch] = *(const float4*)&wrow[ch * 16 + o];
  #pragma unroll
  for (int r = 0; r < 4; ++r) {
    const float* xr = (r == 0) ? x0 : (r == 1) ? x1 : (r == 2) ? x2 : x3;
    float ax = 0.f, ay = 0.f, az = 0.f, aw = 0.f;
    #pragma unroll
    for (int ch = 0; ch < 2; ++ch) {
      float4 x = *(const float4*)&xr[ch * 16 + o];
      ax = fmaf(x.x, wf[ch].x, ax); ay = fmaf(x.y, wf[ch].y, ay);
      az = fmaf(x.z, wf[ch].z, az); aw = fmaf(x.w, wf[ch].w, aw);
    }
    accs[r] += (ax + ay) + (az + aw);
  }
}

// ================================================================
// K12ws r21 (unchanged except OUT_QV zeroing): weight-stationary front,
// 4 rows/block, grid 384, 512 threads, cluster-coalesced weight access.
// Block 0 additionally zeroes out[OUT_QV..+768) so the epi can accumulate
// q_values with atomics (k8 folded into epi — saves a launch).
// Blocks 0..191   (E): obs -> eo -> x_e -> qkv_e
// Blocks 192..383 (A): obs -> L1 -> L2 -> L3/pol -> ea -> x_a -> qkv_a
// ================================================================
__global__ __launch_bounds__(512, 1) void k12ws_front(
    const float* __restrict__ obs,
    const float* __restrict__ aw1, const float* __restrict__ ab1,
    const float* __restrict__ aw2, const float* __restrict__ ab2,
    const float* __restrict__ aw3, const float* __restrict__ ab3,
    const float* __restrict__ eow, const float* __restrict__ eob,
    const float* __restrict__ eaw, const float* __restrict__ eab,
    const float* __restrict__ riw, const float* __restrict__ rib,
    const float* __restrict__ miw, const float* __restrict__ mib,
    float* __restrict__ out, float* __restrict__ ws)
{
  __shared__ float sA[4][256];   // A: h1, then ea in [0..128)  | E: eo
  __shared__ float sB[4][160];   // A: [obs | pol]              | E: obs
  __shared__ float sC[4][128];   // A: h2, then x_a             | E: x_e
  const int t  = threadIdx.x;
  const int bx = blockIdx.x;
  const bool isE = (bx < 192);
  const int r0 = (isE ? bx : bx - 192) * 4;

  const int c  = t >> 2;        // out-col 0..127 (one per 4-lane cluster)
  const int o  = (t & 3) * 4;   // 4-float k-slice within each 16-float chunk
  const bool q0 = (t & 3) == 0;

  if (bx == 0) {                // zero q_values accumulator (768 floats)
    for (int idx = t; idx < 768; idx += 512) out[OUT_QV + idx] = 0.f;
  }

  { // stage obs: 512 floats, 512 threads (coalesced)
    int ri = t >> 7, k = t & 127;
    sB[ri][k] = obs[(r0 + ri) * 128 + k];
  }
  __syncthreads();
  PHASE_FENCE();

  if (isE) {
    { // ---- eo ----
      float accs[4] = {0.f, 0.f, 0.f, 0.f};
      cdot8(eow + (size_t)c * 128, o,
            sB[0], sB[1], sB[2], sB[3], accs);
      const float bias = eob[c];
      #pragma unroll
      for (int r = 0; r < 4; ++r) {
        float acc = accs[r];
        acc += __shfl_xor(acc, 1);
        acc += __shfl_xor(acc, 2);
        if (q0) {
          float v = acc + bias;
          sA[r][c] = v;
          out[OUT_EO + (r0 + r) * 128 + c] = v;
        }
      }
    }
    __syncthreads();
    PHASE_FENCE();
    { // ---- x_e ----
      float accs[4] = {0.f, 0.f, 0.f, 0.f};
      cdot8(riw + (size_t)c * 128, o,
            sA[0], sA[1], sA[2], sA[3], accs);
      const float bias = rib[c];
      #pragma unroll
      for (int r = 0; r < 4; ++r) {
        float acc = accs[r];
        acc += __shfl_xor(acc, 1);
        acc += __shfl_xor(acc, 2);
        if (q0) {
          float v = fmaxf(acc + bias, 0.f);
          sC[r][c] = v;
          ws[OFF_XE + (r0 + r) * 128 + c] = v;
        }
      }
    }
    __syncthreads();
    PHASE_FENCE();
    // ---- qkv_e (3 col-groups) ----
    #pragma unroll 1
    for (int g = 0; g < 3; ++g) {
      float accs[4] = {0.f, 0.f, 0.f, 0.f};
      cdot8(miw + (size_t)(g * 128 + c) * 128, o,
            sC[0], sC[1], sC[2], sC[3], accs);
      const float bias = mib[g * 128 + c];
      #pragma unroll
      for (int r = 0; r < 4; ++r) {
        float acc = accs[r];
        acc += __shfl_xor(acc, 1);
        acc += __shfl_xor(acc, 2);
        if (q0)
          ws[OFF_QKVE + (size_t)(r0 + r) * 384 + g * 128 + c] = acc + bias;
      }
    }
  } else {
    // ---- L1 (2 col-groups) ----
    #pragma unroll 1
    for (int g = 0; g < 2; ++g) {
      float accs[4] = {0.f, 0.f, 0.f, 0.f};
      cdot8(aw1 + (size_t)(g * 128 + c) * 128, o,
            sB[0], sB[1], sB[2], sB[3], accs);
      const float bias = ab1[g * 128 + c];
      #pragma unroll
      for (int r = 0; r < 4; ++r) {
        float acc = accs[r];
        acc += __shfl_xor(acc, 1);
        acc += __shfl_xor(acc, 2);
        if (q0) sA[r][g * 128 + c] = lrelu(acc + bias);
      }
    }
    __syncthreads();
    PHASE_FENCE();
    { // ---- L2 (K=256: two 128-halves, serial cdot8 pair) ----
      float accs[4] = {0.f, 0.f, 0.f, 0.f};
      cdot8(aw2 + (size_t)c * 256, o,
            &sA[0][0], &sA[1][0], &sA[2][0], &sA[3][0], accs);
      cdot8(aw2 + (size_t)c * 256 + 128, o,
            &sA[0][128], &sA[1][128], &sA[2][128], &sA[3][128], accs);
      const float bias = ab2[c];
      #pragma unroll
      for (int r = 0; r < 4; ++r) {
        float acc = accs[r];
        acc += __shfl_xor(acc, 1);
        acc += __shfl_xor(acc, 2);
        if (q0) sC[r][c] = lrelu(acc + bias);
      }
    }
    __syncthreads();
    PHASE_FENCE();
    // ---- L3 + GELU (threads 0..127: 32 cols x 4 q) ----
    if (t < 128) {
      const int c2 = t >> 2;
      float accs[4] = {0.f, 0.f, 0.f, 0.f};
      cdot8(aw3 + (size_t)c2 * 128, o,
            sC[0], sC[1], sC[2], sC[3], accs);
      const float bias = ab3[c2];
      #pragma unroll
      for (int r = 0; r < 4; ++r) {
        float acc = accs[r];
        acc += __shfl_xor(acc, 1);
        acc += __shfl_xor(acc, 2);
        if ((t & 3) == 0) {
          float a = acc + bias;
          float g = 0.5f * a * (1.f + erff(a * 0.70710678118654752f));
          sB[r][128 + c2] = g;
          out[OUT_POL + (r0 + r) * 32 + c2] = g;
        }
      }
    }
    __syncthreads();
    PHASE_FENCE();
    { // ---- ea (K=160: 8 chunks over obs + 2 chunks over pol) ----
      float accs[4] = {0.f, 0.f, 0.f, 0.f};
      const float* wb = eaw + (size_t)c * 160;
      cdot8(wb, o, sB[0], sB[1], sB[2], sB[3], accs);
      cdot2(wb + 128, o,
            &sB[0][128], &sB[1][128], &sB[2][128], &sB[3][128], accs);
      const float bias = eab[c];
      #pragma unroll
      for (int r = 0; r < 4; ++r) {
        float acc = accs[r];
        acc += __shfl_xor(acc, 1);
        acc += __shfl_xor(acc, 2);
        if (q0) sA[r][c] = acc + bias;
      }
    }
    __syncthreads();
    PHASE_FENCE();
    { // ---- x_a ----
      float accs[4] = {0.f, 0.f, 0.f, 0.f};
      cdot8(riw + (size_t)c * 128, o,
            sA[0], sA[1], sA[2], sA[3], accs);
      const float bias = rib[c];
      #pragma unroll
      for (int r = 0; r < 4; ++r) {
        float acc = accs[r];
        acc += __shfl_xor(acc, 1);
        acc += __shfl_xor(acc, 2);
        if (q0) {
          float v = fmaxf(acc + bias, 0.f);
          sC[r][c] = v;
          ws[OFF_XA + (r0 + r) * 128 + c] = v;
        }
      }
    }
    __syncthreads();
    PHASE_FENCE();
    // ---- qkv_a (3 col-groups) ----
    #pragma unroll 1
    for (int g = 0; g < 3; ++g) {
      float accs[4] = {0.f, 0.f, 0.f, 0.f};
      cdot8(miw + (size_t)(g * 128 + c) * 128, o,
            sC[0], sC[1], sC[2], sC[3], accs);
      const float bias = mib[g * 128 + c];
      #pragma unroll
      for (int r = 0; r < 4; ++r) {
        float acc = accs[r];
        acc += __shfl_xor(acc, 1);
        acc += __shfl_xor(acc, 2);
        if (q0)
          ws[OFF_QKVA + (size_t)(r0 + r) * 384 + g * 128 + c] = acc + bias;
      }
    }
  }
}

// ================================================================
// K356: fused attention (r15 exact).
// ================================================================
__global__ __launch_bounds__(256) void k356_attn(float* __restrict__ ws)
{
  __shared__ __align__(16) union {
    struct { float Qs[16 * 36]; float KsT[32 * 68]; float VsT[32 * 68]; float Ss[16 * 68]; } e;
    struct { float Qb[48 * 33]; float Ka[96 * 33]; float Va[96 * 36]; float Ss[48 * 97]; float rinv[48]; } a;
  } su;
  const int t  = threadIdx.x;
  const int bx = blockIdx.x;

  if (bx < 768) {
    const int l0 = (bx % 48) * 16, h = (bx / 48) & 3, sp = bx / 192;
    const float* qkve = ws + OFF_QKVE;

    for (int f = t; f < 512; f += 256)
      su.e.Qs[(f >> 5) * 36 + (f & 31)] = qkve[(size_t)(l0 + (f >> 5)) * 384 + h * 32 + (f & 31)];
    __syncthreads();

    const int l = t >> 4, j = t & 15, c0 = j * 4;
    float q[32];
    #pragma unroll
    for (int dd = 0; dd < 8; ++dd) {
      float4 qq = *(const float4*)&su.e.Qs[l * 36 + dd * 4];
      q[dd*4+0] = qq.x; q[dd*4+1] = qq.y; q[dd*4+2] = qq.z; q[dd*4+3] = qq.w;
    }
    float o0 = 0.f, o1 = 0.f, dsum = 0.f;

    for (int mt = sp * 3; mt < sp * 3 + 3; ++mt) {
      const int m0 = mt * 64;
      __syncthreads();
      for (int f = t; f < 2048; f += 256) {
        int i = f >> 5, d = f & 31;
        const float* src = qkve + (size_t)(m0 + i) * 384 + h * 32 + d;
        su.e.KsT[d * 68 + i] = src[128];
        su.e.VsT[d * 68 + i] = src[256];
      }
      __syncthreads();

      float s0 = 0.f, s1 = 0.f, s2 = 0.f, s3 = 0.f;
      #pragma unroll
      for (int d = 0; d < 32; ++d) {
        float4 kk = *(const float4*)&su.e.KsT[d * 68 + c0];
        s0 = fmaf(q[d], kk.x, s0); s1 = fmaf(q[d], kk.y, s1);
        s2 = fmaf(q[d], kk.z, s2); s3 = fmaf(q[d], kk.w, s3);
      }
      s0 = expf(s0 * SCALE_ATTN); s1 = expf(s1 * SCALE_ATTN);
      s2 = expf(s2 * SCALE_ATTN); s3 = expf(s3 * SCALE_ATTN);
      float4 sv; sv.x = s0; sv.y = s1; sv.z = s2; sv.w = s3;
      *(float4*)&su.e.Ss[l * 68 + c0] = sv;
      float psum = (s0 + s1) + (s2 + s3);
      psum += __shfl_xor(psum, 1); psum += __shfl_xor(psum, 2);
      psum += __shfl_xor(psum, 4); psum += __shfl_xor(psum, 8);
      dsum += psum;

      float t0x=0.f,t0y=0.f,t0z=0.f,t0w=0.f, t1x=0.f,t1y=0.f,t1z=0.f,t1w=0.f;
      #pragma unroll
      for (int k4 = 0; k4 < 16; ++k4) {
        float4 p  = *(const float4*)&su.e.Ss[l * 68 + k4 * 4];
        float4 va = *(const float4*)&su.e.VsT[j * 68 + k4 * 4];
        float4 vb = *(const float4*)&su.e.VsT[(j + 16) * 68 + k4 * 4];
        t0x = fmaf(p.x, va.x, t0x); t0y = fmaf(p.y, va.y, t0y);
        t0z = fmaf(p.z, va.z, t0z); t0w = fmaf(p.w, va.w, t0w);
        t1x = fmaf(p.x, vb.x, t1x); t1y = fmaf(p.y, vb.y, t1y);
        t1z = fmaf(p.z, vb.z, t1z); t1w = fmaf(p.w, vb.w, t1w);
      }
      o0 += (t0x + t0y) + (t0z + t0w);
      o1 += (t1x + t1y) + (t1z + t1w);
    }

    float* aop = ws + OFF_AOP + (size_t)sp * 98304;
    aop[(size_t)(l0 + l) * 128 + h * 32 + j]      = o0;
    aop[(size_t)(l0 + l) * 128 + h * 32 + j + 16] = o1;
    if (j == 0) ws[OFF_DEN + sp * 3072 + (l0 + l) * 4 + h] = dsum;
  } else {
    const int z  = bx - 768;
    const int j1 = z >> 3;
    const int h  = (z & 7) >> 1, rb = z & 1;
    const int jj = j1 + 1;
    const float* qkva = ws + OFF_QKVA;

    for (int f = t; f < 3072; f += 256) {
      int ml = f >> 5, d = f & 31;
      int bp = ml >> 1, spar = ml & 1;
      int ag = spar ? jj : (jj - 1);
      const float* src = qkva + (size_t)(bp * 16 + ag) * 384 + h * 32 + d;
      su.a.Ka[ml * 33 + d] = src[128];
      su.a.Va[ml * 36 + d] = src[256];
    }
    for (int f = t; f < 1536; f += 256) {
      int ql = f >> 5, d = f & 31;
      int Lb = rb * 48 + ql;
      int b = Lb >> 1, s = Lb & 1;
      int ag = s ? jj : (jj - 1);
      su.a.Qb[ql * 33 + d] = qkva[(size_t)(b * 16 + ag) * 384 + h * 32 + d];
    }
    __syncthreads();

    {
      const int tl = (t >> 4) * 3, tm = (t & 15) * 6;
      float acc[3][6] = {{0.f}};
      #pragma unroll
      for (int d = 0; d < 32; ++d) {
        float qv[3], kv[6];
        #pragma unroll
        for (int r = 0; r < 3; ++r) qv[r] = su.a.Qb[(tl + r) * 33 + d];
        #pragma unroll
        for (int c = 0; c < 6; ++c) kv[c] = su.a.Ka[(tm + c) * 33 + d];
        #pragma unroll
        for (int r = 0; r < 3; ++r)
          #pragma unroll
          for (int c = 0; c < 6; ++c) acc[r][c] = fmaf(qv[r], kv[c], acc[r][c]);
      }
      const float wj = (float)jj, wnj = (float)(16 - jj);
      float rs[3] = {0.f, 0.f, 0.f};
      #pragma unroll
      for (int r = 0; r < 3; ++r)
        #pragma unroll
        for (int c = 0; c < 6; ++c) {
          float w = ((tm + c) & 1) ? wj : wnj;
          float p = w * expf(acc[r][c] * SCALE_ATTN);
          su.a.Ss[(tl + r) * 97 + tm + c] = p;
          rs[r] += p;
        }
      #pragma unroll
      for (int r = 0; r < 3; ++r) {
        rs[r] += __shfl_xor(rs[r], 1); rs[r] += __shfl_xor(rs[r], 2);
        rs[r] += __shfl_xor(rs[r], 4); rs[r] += __shfl_xor(rs[r], 8);
      }
      if ((t & 15) == 0) {
        su.a.rinv[tl + 0] = 1.f / rs[0];
        su.a.rinv[tl + 1] = 1.f / rs[1];
        su.a.rinv[tl + 2] = 1.f / rs[2];
      }
    }
    __syncthreads();

    if (t < 192) {
      const int l0 = (t >> 3) * 2, d0 = (t & 7) * 4;
      float a0x=0.f,a0y=0.f,a0z=0.f,a0w=0.f, a1x=0.f,a1y=0.f,a1z=0.f,a1w=0.f;
      for (int m = 0; m < 96; ++m) {
        float p0 = su.a.Ss[l0 * 97 + m], p1 = su.a.Ss[(l0 + 1) * 97 + m];
        float4 v = *(const float4*)&su.a.Va[m * 36 + d0];
        a0x = fmaf(p0, v.x, a0x); a0y = fmaf(p0, v.y, a0y);
        a0z = fmaf(p0, v.z, a0z); a0w = fmaf(p0, v.w, a0w);
        a1x = fmaf(p1, v.x, a1x); a1y = fmaf(p1, v.y, a1y);
        a1z = fmaf(p1, v.z, a1z); a1w = fmaf(p1, v.w, a1w);
      }
      const float s0 = su.a.rinv[l0], s1 = su.a.rinv[l0 + 1];
      float* ao = ws + OFF_AOA + (size_t)(j1 * 96 + rb * 48 + l0) * 128 + h * 32 + d0;
      float4 o0; o0.x = a0x * s0; o0.y = a0y * s0; o0.z = a0z * s0; o0.w = a0w * s0;
      float4 o1; o1.x = a1x * s1; o1.y = a1y * s1; o1.z = a1z * s1; o1.w = a1w * s1;
      *(float4*)ao = o0;
      *(float4*)(ao + 128) = o1;
    }
  }
}

// ================================================================
// K7ab r23: merged epilogue — r15-exact dot structure (256 threads; r22's
// cluster version was +5us, reverted). Tail CHANGED: k8 folded in — each
// row's qv is scattered into out[OUT_QV] with atomics (e-row: 1 add;
// a-row rr=(j-1)*96+b*2+s: adds to i>=j if s==0 else i<j). Each
// contribution carries its own +qb (reference sums 16 rows each with qb).
// Front zeroes out[OUT_QV..+768) before this kernel runs.
// ================================================================
__global__ __launch_bounds__(256) void k7ab_epi(
    const float* __restrict__ mow, const float* __restrict__ mob,
    const float* __restrict__ roww, const float* __restrict__ robb,
    const float* __restrict__ qw,  const float* __restrict__ qb,
    float* __restrict__ ws, float* __restrict__ out)
{
  __shared__ float rows_in[8][132];
  __shared__ float res[8][132];
  __shared__ float t1s[8][132];
  __shared__ float qpart[8][4];
  const int t  = threadIdx.x;
  const int r0 = blockIdx.x * 8;

  for (int s = t; s < 1024; s += 256) {
    int ri = s >> 7, c = s & 127;
    int r = r0 + ri;
    float aoval, x1v;
    if (r < 768) {
      float num = ws[OFF_AOP + 0*98304 + (size_t)r*128 + c]
                + ws[OFF_AOP + 1*98304 + (size_t)r*128 + c]
                + ws[OFF_AOP + 2*98304 + (size_t)r*128 + c]
                + ws[OFF_AOP + 3*98304 + (size_t)r*128 + c];
      int hh = c >> 5;
      float den = ws[OFF_DEN + 0*3072 + r*4 + hh] + ws[OFF_DEN + 1*3072 + r*4 + hh]
                + ws[OFF_DEN + 2*3072 + r*4 + hh] + ws[OFF_DEN + 3*3072 + r*4 + hh];
      aoval = num / den;
      x1v = ws[OFF_XE + r*128 + c];
    } else {
      int rr = r - 768;
      aoval = ws[OFF_AOA + (size_t)rr*128 + c];
      int jx = rr / 96, l96 = rr % 96;
      int b = l96 >> 1, sa = l96 & 1;
      int ag = sa ? (jx + 1) : jx;
      x1v = ws[OFF_XA + (b*16 + ag)*128 + c];
    }
    rows_in[ri][c] = aoval;
    res[ri][c] = x1v;
  }

  const int c = (t & 31) | ((t >> 6) << 5);
  const int h = (t >> 5) & 1;
  __syncthreads();

  { // t1 phase (runtime-looped chunks)
    float accs[8] = {0.f,0.f,0.f,0.f,0.f,0.f,0.f,0.f};
    const float* wb = mow + c * 128 + h * 64;
    #pragma unroll 1
    for (int ch = 0; ch < 2; ++ch) {
      const float4* wp = (const float4*)(wb + ch * 32);
      float4 wf[8];
      #pragma unroll
      for (int i = 0; i < 8; ++i) wf[i] = wp[i];
      #pragma unroll
      for (int ri = 0; ri < 8; ++ri) {
        const float* xr = &rows_in[ri][h * 64 + ch * 32];
        float ax = 0.f, ay = 0.f, az = 0.f, aw = 0.f;
        #pragma unroll
        for (int i = 0; i < 8; ++i) {
          float4 x = *(const float4*)&xr[i * 4];
          ax = fmaf(x.x, wf[i].x, ax); ay = fmaf(x.y, wf[i].y, ay);
          az = fmaf(x.z, wf[i].z, az); aw = fmaf(x.w, wf[i].w, aw);
        }
        accs[ri] += (ax + ay) + (az + aw);
      }
    }
    const float bias = mob[c];
    #pragma unroll
    for (int ri = 0; ri < 8; ++ri) {
      float acc = accs[ri];
      acc += __shfl_xor(acc, 32);
      if (h == 0) t1s[ri][c] = acc + bias + res[ri][c];
    }
  }
  __syncthreads();

  { // ctx + qv phase
    float accs[8] = {0.f,0.f,0.f,0.f,0.f,0.f,0.f,0.f};
    const float* wb = roww + c * 128 + h * 64;
    #pragma unroll 1
    for (int ch = 0; ch < 2; ++ch) {
      const float4* wp = (const float4*)(wb + ch * 32);
      float4 wf[8];
      #pragma unroll
      for (int i = 0; i < 8; ++i) wf[i] = wp[i];
      #pragma unroll
      for (int ri = 0; ri < 8; ++ri) {
        const float* xr = &t1s[ri][h * 64 + ch * 32];
        float ax = 0.f, ay = 0.f, az = 0.f, aw = 0.f;
        #pragma unroll
        for (int i = 0; i < 8; ++i) {
          float4 x = *(const float4*)&xr[i * 4];
          ax = fmaf(x.x, wf[i].x, ax); ay = fmaf(x.y, wf[i].y, ay);
          az = fmaf(x.z, wf[i].z, az); aw = fmaf(x.w, wf[i].w, aw);
        }
        accs[ri] += (ax + ay) + (az + aw);
      }
    }
    const float bias = robb[c];
    const float qwc  = qw[c];
    #pragma unroll
    for (int ri = 0; ri < 8; ++ri) {
      float acc = accs[ri];
      acc += __shfl_xor(acc, 32);
      float ctx = fmaxf(acc + bias, 0.f);
      float p = (h == 0) ? qwc * ctx : 0.f;
      p += __shfl_xor(p, 1);  p += __shfl_xor(p, 2);  p += __shfl_xor(p, 4);
      p += __shfl_xor(p, 8);  p += __shfl_xor(p, 16); p += __shfl_xor(p, 32);
      if ((t & 63) == 0) qpart[ri][t >> 6] = p;
    }
  }
  __syncthreads();

  if (t < 8) {
    float qv = (qpart[t][0] + qpart[t][1]) + (qpart[t][2] + qpart[t][3]) + qb[0];
    int r = r0 + t;
    if (r < 768) {
      atomicAdd(&out[OUT_QV + r], qv);
    } else {
      int rr = r - 768;
      int jx = rr / 96, l96 = rr % 96;
      int b = l96 >> 1, sa = l96 & 1;
      int jj = jx + 1;
      // s==0 row feeds i >= jj ; s==1 row feeds i < jj
      int ibeg = sa ? 0 : jj;
      int iend = sa ? jj : 16;
      for (int i = ibeg; i < iend; ++i)
        atomicAdd(&out[OUT_QV + b * 16 + i], qv);
    }
  }
}

// ================================================================
extern "C" void kernel_launch(void* const* d_in, const int* in_sizes, int n_in,
                              void* d_out, int out_size, void* d_ws, size_t ws_size,
                              hipStream_t stream)
{
  (void)in_sizes; (void)n_in; (void)out_size;
  if (ws_size < (size_t)WS_FLOATS * 4) return;

  const float* obs = (const float*)d_in[0];
  const float* aw1 = (const float*)d_in[1];
  const float* ab1 = (const float*)d_in[2];
  const float* aw2 = (const float*)d_in[3];
  const float* ab2 = (const float*)d_in[4];
  const float* aw3 = (const float*)d_in[5];
  const float* ab3 = (const float*)d_in[6];
  const float* eow = (const float*)d_in[7];
  const float* eob = (const float*)d_in[8];
  const float* eaw = (const float*)d_in[9];
  const float* eab = (const float*)d_in[10];
  const float* riw = (const float*)d_in[11];
  const float* rib = (const float*)d_in[12];
  const float* roww= (const float*)d_in[13];
  const float* robb= (const float*)d_in[14];
  const float* miw = (const float*)d_in[15];
  const float* mib = (const float*)d_in[16];
  const float* mow = (const float*)d_in[17];
  const float* mob = (const float*)d_in[18];
  const float* qw  = (const float*)d_in[19];
  const float* qb  = (const float*)d_in[20];

  float* out = (float*)d_out;
  float* ws  = (float*)d_ws;

  k12ws_front<<<dim3(384), dim3(512), 0, stream>>>(obs, aw1, ab1, aw2, ab2, aw3, ab3,
                                                   eow, eob, eaw, eab, riw, rib, miw, mib,
                                                   out, ws);
  k356_attn<<<dim3(888), dim3(256), 0, stream>>>(ws);
  k7ab_epi<<<dim3(276), dim3(256), 0, stream>>>(mow, mob, roww, robb, qw, qb, ws, out);
}

// Round 9
// 157.102 us; speedup vs baseline: 1.0737x; 1.0285x over previous
//
#include <hip/hip_runtime.h>
#include <math.h>

static __device__ __forceinline__ float lrelu(float x){ return x > 0.f ? x : 0.01f * x; }

// ---- workspace layout (float offsets) ----
#define OFF_XE    196608
#define OFF_XA    294912
#define OFF_QKVE  393216
#define OFF_QKVA  688128
#define OFF_AOP   983040    // 4 splits * 768*128
#define OFF_DEN   1376256   // 4 splits * 768*4
#define OFF_AOA   1388544   // 15*96*128
#define WS_FLOATS 1575072

// ---- output layout (fp32 elems) ----
#define OUT_POL 0
#define OUT_QV  24576
#define OUT_EO  25344

#define SCALE_ATTN 0.17677669529663689f  // 1/sqrt(32)

// Phase fence: keeps the compiler from hoisting later phases' weight loads
// across __syncthreads (r17 lesson: VGPR 256 + spill).
#define PHASE_FENCE() __builtin_amdgcn_sched_barrier(0)

// r21 cdot8 (PROVEN WIN): cluster-coalesced weight dot. c=t>>2, o=(t&3)*4:
// each 4-lane cluster owns one output column and reads 16 CONSECUTIVE floats
// of W-row c per chunk -> 16 cache lines per wave-load vs 64 for the
// per-lane-row layout (front 40.9 -> ~33, total -8us). These phases are
// L1-line-transaction bound (TLP/balance/conflict fixes all null r19/r20).
static __device__ __forceinline__ void cdot8(
    const float* __restrict__ wrow, int o,   // o = (t&3)*4
    const float* __restrict__ x0, const float* __restrict__ x1,
    const float* __restrict__ x2, const float* __restrict__ x3,
    float* __restrict__ accs)
{
  float4 wf[8];
  #pragma unroll
  for (int ch = 0; ch < 8; ++ch)
    wf[ch] = *(const float4*)&wrow[ch * 16 + o];
  #pragma unroll
  for (int r = 0; r < 4; ++r) {
    const float* xr = (r == 0) ? x0 : (r == 1) ? x1 : (r == 2) ? x2 : x3;
    float ax = 0.f, ay = 0.f, az = 0.f, aw = 0.f;
    #pragma unroll
    for (int ch = 0; ch < 8; ++ch) {
      float4 x = *(const float4*)&xr[ch * 16 + o];
      ax = fmaf(x.x, wf[ch].x, ax); ay = fmaf(x.y, wf[ch].y, ay);
      az = fmaf(x.z, wf[ch].z, az); aw = fmaf(x.w, wf[ch].w, aw);
    }
    accs[r] += (ax + ay) + (az + aw);
  }
}

// 2-chunk (32-float) variant for K=160's tail region.
static __device__ __forceinline__ void cdot2(
    const float* __restrict__ wrow, int o,
    const float* __restrict__ x0, const float* __restrict__ x1,
    const float* __restrict__ x2, const float* __restrict__ x3,
    float* __restrict__ accs)
{
  float4 wf[2];
  #pragma unroll
  for (int ch = 0; ch < 2; ++ch)
    wf[ch] = *(const float4*)&wrow[ch * 16 + o];
  #pragma unroll
  for (int r = 0; r < 4; ++r) {
    const float* xr = (r == 0) ? x0 : (r == 1) ? x1 : (r == 2) ? x2 : x3;
    float ax = 0.f, ay = 0.f, az = 0.f, aw = 0.f;
    #pragma unroll
    for (int ch = 0; ch < 2; ++ch) {
      float4 x = *(const float4*)&xr[ch * 16 + o];
      ax = fmaf(x.x, wf[ch].x, ax); ay = fmaf(x.y, wf[ch].y, ay);
      az = fmaf(x.z, wf[ch].z, az); aw = fmaf(x.w, wf[ch].w, aw);
    }
    accs[r] += (ax + ay) + (az + aw);
  }
}

// ================================================================
// K12ws (r23 exact): weight-stationary front, 4 rows/block, grid 384,
// 512 threads, cluster-coalesced weight access. Block 0 zeroes
// out[OUT_QV..+768) for the epi's atomic q_values accumulation.
// Blocks 0..191   (E): obs -> eo -> x_e -> qkv_e
// Blocks 192..383 (A): obs -> L1 -> L2 -> L3/pol -> ea -> x_a -> qkv_a
// ================================================================
__global__ __launch_bounds__(512, 1) void k12ws_front(
    const float* __restrict__ obs,
    const float* __restrict__ aw1, const float* __restrict__ ab1,
    const float* __restrict__ aw2, const float* __restrict__ ab2,
    const float* __restrict__ aw3, const float* __restrict__ ab3,
    const float* __restrict__ eow, const float* __restrict__ eob,
    const float* __restrict__ eaw, const float* __restrict__ eab,
    const float* __restrict__ riw, const float* __restrict__ rib,
    const float* __restrict__ miw, const float* __restrict__ mib,
    float* __restrict__ out, float* __restrict__ ws)
{
  __shared__ float sA[4][256];   // A: h1, then ea in [0..128)  | E: eo
  __shared__ float sB[4][160];   // A: [obs | pol]              | E: obs
  __shared__ float sC[4][128];   // A: h2, then x_a             | E: x_e
  const int t  = threadIdx.x;
  const int bx = blockIdx.x;
  const bool isE = (bx < 192);
  const int r0 = (isE ? bx : bx - 192) * 4;

  const int c  = t >> 2;        // out-col 0..127 (one per 4-lane cluster)
  const int o  = (t & 3) * 4;   // 4-float k-slice within each 16-float chunk
  const bool q0 = (t & 3) == 0;

  if (bx == 0) {                // zero q_values accumulator (768 floats)
    for (int idx = t; idx < 768; idx += 512) out[OUT_QV + idx] = 0.f;
  }

  { // stage obs: 512 floats, 512 threads (coalesced)
    int ri = t >> 7, k = t & 127;
    sB[ri][k] = obs[(r0 + ri) * 128 + k];
  }
  __syncthreads();
  PHASE_FENCE();

  if (isE) {
    { // ---- eo ----
      float accs[4] = {0.f, 0.f, 0.f, 0.f};
      cdot8(eow + (size_t)c * 128, o,
            sB[0], sB[1], sB[2], sB[3], accs);
      const float bias = eob[c];
      #pragma unroll
      for (int r = 0; r < 4; ++r) {
        float acc = accs[r];
        acc += __shfl_xor(acc, 1);
        acc += __shfl_xor(acc, 2);
        if (q0) {
          float v = acc + bias;
          sA[r][c] = v;
          out[OUT_EO + (r0 + r) * 128 + c] = v;
        }
      }
    }
    __syncthreads();
    PHASE_FENCE();
    { // ---- x_e ----
      float accs[4] = {0.f, 0.f, 0.f, 0.f};
      cdot8(riw + (size_t)c * 128, o,
            sA[0], sA[1], sA[2], sA[3], accs);
      const float bias = rib[c];
      #pragma unroll
      for (int r = 0; r < 4; ++r) {
        float acc = accs[r];
        acc += __shfl_xor(acc, 1);
        acc += __shfl_xor(acc, 2);
        if (q0) {
          float v = fmaxf(acc + bias, 0.f);
          sC[r][c] = v;
          ws[OFF_XE + (r0 + r) * 128 + c] = v;
        }
      }
    }
    __syncthreads();
    PHASE_FENCE();
    // ---- qkv_e (3 col-groups) ----
    #pragma unroll 1
    for (int g = 0; g < 3; ++g) {
      float accs[4] = {0.f, 0.f, 0.f, 0.f};
      cdot8(miw + (size_t)(g * 128 + c) * 128, o,
            sC[0], sC[1], sC[2], sC[3], accs);
      const float bias = mib[g * 128 + c];
      #pragma unroll
      for (int r = 0; r < 4; ++r) {
        float acc = accs[r];
        acc += __shfl_xor(acc, 1);
        acc += __shfl_xor(acc, 2);
        if (q0)
          ws[OFF_QKVE + (size_t)(r0 + r) * 384 + g * 128 + c] = acc + bias;
      }
    }
  } else {
    // ---- L1 (2 col-groups) ----
    #pragma unroll 1
    for (int g = 0; g < 2; ++g) {
      float accs[4] = {0.f, 0.f, 0.f, 0.f};
      cdot8(aw1 + (size_t)(g * 128 + c) * 128, o,
            sB[0], sB[1], sB[2], sB[3], accs);
      const float bias = ab1[g * 128 + c];
      #pragma unroll
      for (int r = 0; r < 4; ++r) {
        float acc = accs[r];
        acc += __shfl_xor(acc, 1);
        acc += __shfl_xor(acc, 2);
        if (q0) sA[r][g * 128 + c] = lrelu(acc + bias);
      }
    }
    __syncthreads();
    PHASE_FENCE();
    { // ---- L2 (K=256: two 128-halves, serial cdot8 pair) ----
      float accs[4] = {0.f, 0.f, 0.f, 0.f};
      cdot8(aw2 + (size_t)c * 256, o,
            &sA[0][0], &sA[1][0], &sA[2][0], &sA[3][0], accs);
      cdot8(aw2 + (size_t)c * 256 + 128, o,
            &sA[0][128], &sA[1][128], &sA[2][128], &sA[3][128], accs);
      const float bias = ab2[c];
      #pragma unroll
      for (int r = 0; r < 4; ++r) {
        float acc = accs[r];
        acc += __shfl_xor(acc, 1);
        acc += __shfl_xor(acc, 2);
        if (q0) sC[r][c] = lrelu(acc + bias);
      }
    }
    __syncthreads();
    PHASE_FENCE();
    // ---- L3 + GELU (threads 0..127: 32 cols x 4 q) ----
    if (t < 128) {
      const int c2 = t >> 2;
      float accs[4] = {0.f, 0.f, 0.f, 0.f};
      cdot8(aw3 + (size_t)c2 * 128, o,
            sC[0], sC[1], sC[2], sC[3], accs);
      const float bias = ab3[c2];
      #pragma unroll
      for (int r = 0; r < 4; ++r) {
        float acc = accs[r];
        acc += __shfl_xor(acc, 1);
        acc += __shfl_xor(acc, 2);
        if ((t & 3) == 0) {
          float a = acc + bias;
          float g = 0.5f * a * (1.f + erff(a * 0.70710678118654752f));
          sB[r][128 + c2] = g;
          out[OUT_POL + (r0 + r) * 32 + c2] = g;
        }
      }
    }
    __syncthreads();
    PHASE_FENCE();
    { // ---- ea (K=160: 8 chunks over obs + 2 chunks over pol) ----
      float accs[4] = {0.f, 0.f, 0.f, 0.f};
      const float* wb = eaw + (size_t)c * 160;
      cdot8(wb, o, sB[0], sB[1], sB[2], sB[3], accs);
      cdot2(wb + 128, o,
            &sB[0][128], &sB[1][128], &sB[2][128], &sB[3][128], accs);
      const float bias = eab[c];
      #pragma unroll
      for (int r = 0; r < 4; ++r) {
        float acc = accs[r];
        acc += __shfl_xor(acc, 1);
        acc += __shfl_xor(acc, 2);
        if (q0) sA[r][c] = acc + bias;
      }
    }
    __syncthreads();
    PHASE_FENCE();
    { // ---- x_a ----
      float accs[4] = {0.f, 0.f, 0.f, 0.f};
      cdot8(riw + (size_t)c * 128, o,
            sA[0], sA[1], sA[2], sA[3], accs);
      const float bias = rib[c];
      #pragma unroll
      for (int r = 0; r < 4; ++r) {
        float acc = accs[r];
        acc += __shfl_xor(acc, 1);
        acc += __shfl_xor(acc, 2);
        if (q0) {
          float v = fmaxf(acc + bias, 0.f);
          sC[r][c] = v;
          ws[OFF_XA + (r0 + r) * 128 + c] = v;
        }
      }
    }
    __syncthreads();
    PHASE_FENCE();
    // ---- qkv_a (3 col-groups) ----
    #pragma unroll 1
    for (int g = 0; g < 3; ++g) {
      float accs[4] = {0.f, 0.f, 0.f, 0.f};
      cdot8(miw + (size_t)(g * 128 + c) * 128, o,
            sC[0], sC[1], sC[2], sC[3], accs);
      const float bias = mib[g * 128 + c];
      #pragma unroll
      for (int r = 0; r < 4; ++r) {
        float acc = accs[r];
        acc += __shfl_xor(acc, 1);
        acc += __shfl_xor(acc, 2);
        if (q0)
          ws[OFF_QKVA + (size_t)(r0 + r) * 384 + g * 128 + c] = acc + bias;
      }
    }
  }
}

// ================================================================
// K356 r24: fused attention — compute identical to r15; staging loads
// VECTORIZED (float4). Staging was all scalar 4B loads sitting exposed
// between barriers (E: 16 loads/thread/tile -> 4; A: 30 -> ~7.5).
// LDS layouts unchanged; odd-stride arrays (KsT/Ka/Qb) take 4 scalar
// ds_writes per float4 (same banks as before); 16B-aligned rows
// (Qs stride 36, Va stride 36) take vector writes.
// ================================================================
__global__ __launch_bounds__(256) void k356_attn(float* __restrict__ ws)
{
  __shared__ __align__(16) union {
    struct { float Qs[16 * 36]; float KsT[32 * 68]; float VsT[32 * 68]; float Ss[16 * 68]; } e;
    struct { float Qb[48 * 33]; float Ka[96 * 33]; float Va[96 * 36]; float Ss[48 * 97]; float rinv[48]; } a;
  } su;
  const int t  = threadIdx.x;
  const int bx = blockIdx.x;

  if (bx < 768) {
    const int l0 = (bx % 48) * 16, h = (bx / 48) & 3, sp = bx / 192;
    const float* qkve = ws + OFF_QKVE;

    // Q: 512 floats = 128 float4; threads 0..127 take one each.
    if (t < 128) {
      int ql = t >> 3, d4 = (t & 7) * 4;
      float4 q4 = *(const float4*)&qkve[(size_t)(l0 + ql) * 384 + h * 32 + d4];
      *(float4*)&su.e.Qs[ql * 36 + d4] = q4;   // (ql*36+d4)*4B is 16B-aligned
    }
    __syncthreads();

    const int l = t >> 4, j = t & 15, c0 = j * 4;
    float q[32];
    #pragma unroll
    for (int dd = 0; dd < 8; ++dd) {
      float4 qq = *(const float4*)&su.e.Qs[l * 36 + dd * 4];
      q[dd*4+0] = qq.x; q[dd*4+1] = qq.y; q[dd*4+2] = qq.z; q[dd*4+3] = qq.w;
    }
    float o0 = 0.f, o1 = 0.f, dsum = 0.f;

    for (int mt = sp * 3; mt < sp * 3 + 3; ++mt) {
      const int m0 = mt * 64;
      __syncthreads();
      // K/V tile: 2048 floats each = 512 float4; 2 float4/thread each.
      #pragma unroll
      for (int j2 = 0; j2 < 2; ++j2) {
        int f4 = t + j2 * 256;               // 0..511
        int i = f4 >> 3, d4 = (f4 & 7) * 4;
        const float* src = qkve + (size_t)(m0 + i) * 384 + h * 32 + d4;
        float4 kk = *(const float4*)&src[128];
        float4 vv = *(const float4*)&src[256];
        su.e.KsT[(d4+0) * 68 + i] = kk.x;
        su.e.KsT[(d4+1) * 68 + i] = kk.y;
        su.e.KsT[(d4+2) * 68 + i] = kk.z;
        su.e.KsT[(d4+3) * 68 + i] = kk.w;
        su.e.VsT[(d4+0) * 68 + i] = vv.x;
        su.e.VsT[(d4+1) * 68 + i] = vv.y;
        su.e.VsT[(d4+2) * 68 + i] = vv.z;
        su.e.VsT[(d4+3) * 68 + i] = vv.w;
      }
      __syncthreads();

      float s0 = 0.f, s1 = 0.f, s2 = 0.f, s3 = 0.f;
      #pragma unroll
      for (int d = 0; d < 32; ++d) {
        float4 kk = *(const float4*)&su.e.KsT[d * 68 + c0];
        s0 = fmaf(q[d], kk.x, s0); s1 = fmaf(q[d], kk.y, s1);
        s2 = fmaf(q[d], kk.z, s2); s3 = fmaf(q[d], kk.w, s3);
      }
      s0 = expf(s0 * SCALE_ATTN); s1 = expf(s1 * SCALE_ATTN);
      s2 = expf(s2 * SCALE_ATTN); s3 = expf(s3 * SCALE_ATTN);
      float4 sv; sv.x = s0; sv.y = s1; sv.z = s2; sv.w = s3;
      *(float4*)&su.e.Ss[l * 68 + c0] = sv;
      float psum = (s0 + s1) + (s2 + s3);
      psum += __shfl_xor(psum, 1); psum += __shfl_xor(psum, 2);
      psum += __shfl_xor(psum, 4); psum += __shfl_xor(psum, 8);
      dsum += psum;

      float t0x=0.f,t0y=0.f,t0z=0.f,t0w=0.f, t1x=0.f,t1y=0.f,t1z=0.f,t1w=0.f;
      #pragma unroll
      for (int k4 = 0; k4 < 16; ++k4) {
        float4 p  = *(const float4*)&su.e.Ss[l * 68 + k4 * 4];
        float4 va = *(const float4*)&su.e.VsT[j * 68 + k4 * 4];
        float4 vb = *(const float4*)&su.e.VsT[(j + 16) * 68 + k4 * 4];
        t0x = fmaf(p.x, va.x, t0x); t0y = fmaf(p.y, va.y, t0y);
        t0z = fmaf(p.z, va.z, t0z); t0w = fmaf(p.w, va.w, t0w);
        t1x = fmaf(p.x, vb.x, t1x); t1y = fmaf(p.y, vb.y, t1y);
        t1z = fmaf(p.z, vb.z, t1z); t1w = fmaf(p.w, vb.w, t1w);
      }
      o0 += (t0x + t0y) + (t0z + t0w);
      o1 += (t1x + t1y) + (t1z + t1w);
    }

    float* aop = ws + OFF_AOP + (size_t)sp * 98304;
    aop[(size_t)(l0 + l) * 128 + h * 32 + j]      = o0;
    aop[(size_t)(l0 + l) * 128 + h * 32 + j + 16] = o1;
    if (j == 0) ws[OFF_DEN + sp * 3072 + (l0 + l) * 4 + h] = dsum;
  } else {
    const int z  = bx - 768;
    const int j1 = z >> 3;
    const int h  = (z & 7) >> 1, rb = z & 1;
    const int jj = j1 + 1;
    const float* qkva = ws + OFF_QKVA;

    // Ka/Va: 3072 floats each = 768 float4; 3 float4/thread each.
    for (int f4 = t; f4 < 768; f4 += 256) {
      int ml = f4 >> 3, d4 = (f4 & 7) * 4;
      int bp = ml >> 1, spar = ml & 1;
      int ag = spar ? jj : (jj - 1);
      const float* src = qkva + (size_t)(bp * 16 + ag) * 384 + h * 32 + d4;
      float4 kk = *(const float4*)&src[128];
      float4 vv = *(const float4*)&src[256];
      su.a.Ka[ml * 33 + d4 + 0] = kk.x;
      su.a.Ka[ml * 33 + d4 + 1] = kk.y;
      su.a.Ka[ml * 33 + d4 + 2] = kk.z;
      su.a.Ka[ml * 33 + d4 + 3] = kk.w;
      *(float4*)&su.a.Va[ml * 36 + d4] = vv;   // stride 36: 16B-aligned
    }
    // Qb: 1536 floats = 384 float4.
    for (int f4 = t; f4 < 384; f4 += 256) {
      int ql = f4 >> 3, d4 = (f4 & 7) * 4;
      int Lb = rb * 48 + ql;
      int b = Lb >> 1, s = Lb & 1;
      int ag = s ? jj : (jj - 1);
      float4 q4 = *(const float4*)&qkva[(size_t)(b * 16 + ag) * 384 + h * 32 + d4];
      su.a.Qb[ql * 33 + d4 + 0] = q4.x;
      su.a.Qb[ql * 33 + d4 + 1] = q4.y;
      su.a.Qb[ql * 33 + d4 + 2] = q4.z;
      su.a.Qb[ql * 33 + d4 + 3] = q4.w;
    }
    __syncthreads();

    {
      const int tl = (t >> 4) * 3, tm = (t & 15) * 6;
      float acc[3][6] = {{0.f}};
      #pragma unroll
      for (int d = 0; d < 32; ++d) {
        float qv[3], kv[6];
        #pragma unroll
        for (int r = 0; r < 3; ++r) qv[r] = su.a.Qb[(tl + r) * 33 + d];
        #pragma unroll
        for (int c = 0; c < 6; ++c) kv[c] = su.a.Ka[(tm + c) * 33 + d];
        #pragma unroll
        for (int r = 0; r < 3; ++r)
          #pragma unroll
          for (int c = 0; c < 6; ++c) acc[r][c] = fmaf(qv[r], kv[c], acc[r][c]);
      }
      const float wj = (float)jj, wnj = (float)(16 - jj);
      float rs[3] = {0.f, 0.f, 0.f};
      #pragma unroll
      for (int r = 0; r < 3; ++r)
        #pragma unroll
        for (int c = 0; c < 6; ++c) {
          float w = ((tm + c) & 1) ? wj : wnj;
          float p = w * expf(acc[r][c] * SCALE_ATTN);
          su.a.Ss[(tl + r) * 97 + tm + c] = p;
          rs[r] += p;
        }
      #pragma unroll
      for (int r = 0; r < 3; ++r) {
        rs[r] += __shfl_xor(rs[r], 1); rs[r] += __shfl_xor(rs[r], 2);
        rs[r] += __shfl_xor(rs[r], 4); rs[r] += __shfl_xor(rs[r], 8);
      }
      if ((t & 15) == 0) {
        su.a.rinv[tl + 0] = 1.f / rs[0];
        su.a.rinv[tl + 1] = 1.f / rs[1];
        su.a.rinv[tl + 2] = 1.f / rs[2];
      }
    }
    __syncthreads();

    if (t < 192) {
      const int l0 = (t >> 3) * 2, d0 = (t & 7) * 4;
      float a0x=0.f,a0y=0.f,a0z=0.f,a0w=0.f, a1x=0.f,a1y=0.f,a1z=0.f,a1w=0.f;
      for (int m = 0; m < 96; ++m) {
        float p0 = su.a.Ss[l0 * 97 + m], p1 = su.a.Ss[(l0 + 1) * 97 + m];
        float4 v = *(const float4*)&su.a.Va[m * 36 + d0];
        a0x = fmaf(p0, v.x, a0x); a0y = fmaf(p0, v.y, a0y);
        a0z = fmaf(p0, v.z, a0z); a0w = fmaf(p0, v.w, a0w);
        a1x = fmaf(p1, v.x, a1x); a1y = fmaf(p1, v.y, a1y);
        a1z = fmaf(p1, v.z, a1z); a1w = fmaf(p1, v.w, a1w);
      }
      const float s0 = su.a.rinv[l0], s1 = su.a.rinv[l0 + 1];
      float* ao = ws + OFF_AOA + (size_t)(j1 * 96 + rb * 48 + l0) * 128 + h * 32 + d0;
      float4 o0; o0.x = a0x * s0; o0.y = a0y * s0; o0.z = a0z * s0; o0.w = a0w * s0;
      float4 o1; o1.x = a1x * s1; o1.y = a1y * s1; o1.z = a1z * s1; o1.w = a1w * s1;
      *(float4*)ao = o0;
      *(float4*)(ao + 128) = o1;
    }
  }
}

// ================================================================
// K7ab (r23 exact): merged epilogue — r15 dot structure (256 threads),
// k8 folded in via atomic scatter of qv into out[OUT_QV].
// ================================================================
__global__ __launch_bounds__(256) void k7ab_epi(
    const float* __restrict__ mow, const float* __restrict__ mob,
    const float* __restrict__ roww, const float* __restrict__ robb,
    const float* __restrict__ qw,  const float* __restrict__ qb,
    float* __restrict__ ws, float* __restrict__ out)
{
  __shared__ float rows_in[8][132];
  __shared__ float res[8][132];
  __shared__ float t1s[8][132];
  __shared__ float qpart[8][4];
  const int t  = threadIdx.x;
  const int r0 = blockIdx.x * 8;

  for (int s = t; s < 1024; s += 256) {
    int ri = s >> 7, c = s & 127;
    int r = r0 + ri;
    float aoval, x1v;
    if (r < 768) {
      float num = ws[OFF_AOP + 0*98304 + (size_t)r*128 + c]
                + ws[OFF_AOP + 1*98304 + (size_t)r*128 + c]
                + ws[OFF_AOP + 2*98304 + (size_t)r*128 + c]
                + ws[OFF_AOP + 3*98304 + (size_t)r*128 + c];
      int hh = c >> 5;
      float den = ws[OFF_DEN + 0*3072 + r*4 + hh] + ws[OFF_DEN + 1*3072 + r*4 + hh]
                + ws[OFF_DEN + 2*3072 + r*4 + hh] + ws[OFF_DEN + 3*3072 + r*4 + hh];
      aoval = num / den;
      x1v = ws[OFF_XE + r*128 + c];
    } else {
      int rr = r - 768;
      aoval = ws[OFF_AOA + (size_t)rr*128 + c];
      int jx = rr / 96, l96 = rr % 96;
      int b = l96 >> 1, sa = l96 & 1;
      int ag = sa ? (jx + 1) : jx;
      x1v = ws[OFF_XA + (b*16 + ag)*128 + c];
    }
    rows_in[ri][c] = aoval;
    res[ri][c] = x1v;
  }

  const int c = (t & 31) | ((t >> 6) << 5);
  const int h = (t >> 5) & 1;
  __syncthreads();

  { // t1 phase (runtime-looped chunks)
    float accs[8] = {0.f,0.f,0.f,0.f,0.f,0.f,0.f,0.f};
    const float* wb = mow + c * 128 + h * 64;
    #pragma unroll 1
    for (int ch = 0; ch < 2; ++ch) {
      const float4* wp = (const float4*)(wb + ch * 32);
      float4 wf[8];
      #pragma unroll
      for (int i = 0; i < 8; ++i) wf[i] = wp[i];
      #pragma unroll
      for (int ri = 0; ri < 8; ++ri) {
        const float* xr = &rows_in[ri][h * 64 + ch * 32];
        float ax = 0.f, ay = 0.f, az = 0.f, aw = 0.f;
        #pragma unroll
        for (int i = 0; i < 8; ++i) {
          float4 x = *(const float4*)&xr[i * 4];
          ax = fmaf(x.x, wf[i].x, ax); ay = fmaf(x.y, wf[i].y, ay);
          az = fmaf(x.z, wf[i].z, az); aw = fmaf(x.w, wf[i].w, aw);
        }
        accs[ri] += (ax + ay) + (az + aw);
      }
    }
    const float bias = mob[c];
    #pragma unroll
    for (int ri = 0; ri < 8; ++ri) {
      float acc = accs[ri];
      acc += __shfl_xor(acc, 32);
      if (h == 0) t1s[ri][c] = acc + bias + res[ri][c];
    }
  }
  __syncthreads();

  { // ctx + qv phase
    float accs[8] = {0.f,0.f,0.f,0.f,0.f,0.f,0.f,0.f};
    const float* wb = roww + c * 128 + h * 64;
    #pragma unroll 1
    for (int ch = 0; ch < 2; ++ch) {
      const float4* wp = (const float4*)(wb + ch * 32);
      float4 wf[8];
      #pragma unroll
      for (int i = 0; i < 8; ++i) wf[i] = wp[i];
      #pragma unroll
      for (int ri = 0; ri < 8; ++ri) {
        const float* xr = &t1s[ri][h * 64 + ch * 32];
        float ax = 0.f, ay = 0.f, az = 0.f, aw = 0.f;
        #pragma unroll
        for (int i = 0; i < 8; ++i) {
          float4 x = *(const float4*)&xr[i * 4];
          ax = fmaf(x.x, wf[i].x, ax); ay = fmaf(x.y, wf[i].y, ay);
          az = fmaf(x.z, wf[i].z, az); aw = fmaf(x.w, wf[i].w, aw);
        }
        accs[ri] += (ax + ay) + (az + aw);
      }
    }
    const float bias = robb[c];
    const float qwc  = qw[c];
    #pragma unroll
    for (int ri = 0; ri < 8; ++ri) {
      float acc = accs[ri];
      acc += __shfl_xor(acc, 32);
      float ctx = fmaxf(acc + bias, 0.f);
      float p = (h == 0) ? qwc * ctx : 0.f;
      p += __shfl_xor(p, 1);  p += __shfl_xor(p, 2);  p += __shfl_xor(p, 4);
      p += __shfl_xor(p, 8);  p += __shfl_xor(p, 16); p += __shfl_xor(p, 32);
      if ((t & 63) == 0) qpart[ri][t >> 6] = p;
    }
  }
  __syncthreads();

  if (t < 8) {
    float qv = (qpart[t][0] + qpart[t][1]) + (qpart[t][2] + qpart[t][3]) + qb[0];
    int r = r0 + t;
    if (r < 768) {
      atomicAdd(&out[OUT_QV + r], qv);
    } else {
      int rr = r - 768;
      int jx = rr / 96, l96 = rr % 96;
      int b = l96 >> 1, sa = l96 & 1;
      int jj = jx + 1;
      // s==0 row feeds i >= jj ; s==1 row feeds i < jj
      int ibeg = sa ? 0 : jj;
      int iend = sa ? jj : 16;
      for (int i = ibeg; i < iend; ++i)
        atomicAdd(&out[OUT_QV + b * 16 + i], qv);
    }
  }
}

// ================================================================
extern "C" void kernel_launch(void* const* d_in, const int* in_sizes, int n_in,
                              void* d_out, int out_size, void* d_ws, size_t ws_size,
                              hipStream_t stream)
{
  (void)in_sizes; (void)n_in; (void)out_size;
  if (ws_size < (size_t)WS_FLOATS * 4) return;

  const float* obs = (const float*)d_in[0];
  const float* aw1 = (const float*)d_in[1];
  const float* ab1 = (const float*)d_in[2];
  const float* aw2 = (const float*)d_in[3];
  const float* ab2 = (const float*)d_in[4];
  const float* aw3 = (const float*)d_in[5];
  const float* ab3 = (const float*)d_in[6];
  const float* eow = (const float*)d_in[7];
  const float* eob = (const float*)d_in[8];
  const float* eaw = (const float*)d_in[9];
  const float* eab = (const float*)d_in[10];
  const float* riw = (const float*)d_in[11];
  const float* rib = (const float*)d_in[12];
  const float* roww= (const float*)d_in[13];
  const float* robb= (const float*)d_in[14];
  const float* miw = (const float*)d_in[15];
  const float* mib = (const float*)d_in[16];
  const float* mow = (const float*)d_in[17];
  const float* mob = (const float*)d_in[18];
  const float* qw  = (const float*)d_in[19];
  const float* qb  = (const float*)d_in[20];

  float* out = (float*)d_out;
  float* ws  = (float*)d_ws;

  k12ws_front<<<dim3(384), dim3(512), 0, stream>>>(obs, aw1, ab1, aw2, ab2, aw3, ab3,
                                                   eow, eob, eaw, eab, riw, rib, miw, mib,
                                                   out, ws);
  k356_attn<<<dim3(888), dim3(256), 0, stream>>>(ws);
  k7ab_epi<<<dim3(276), dim3(256), 0, stream>>>(mow, mob, roww, robb, qw, qb, ws, out);
}

// Round 10
// 154.159 us; speedup vs baseline: 1.0942x; 1.0191x over previous
//
#include <hip/hip_runtime.h>
#include <math.h>

static __device__ __forceinline__ float lrelu(float x){ return x > 0.f ? x : 0.01f * x; }

// ---- workspace layout (float offsets) ----
#define OFF_XE    196608
#define OFF_XA    294912
#define OFF_QKVE  393216
#define OFF_QKVA  688128
#define OFF_AOP   983040    // 4 splits * 768*128
#define OFF_DEN   1376256   // 4 splits * 768*4
#define OFF_AOA   1388544   // 15*96*128
#define WS_FLOATS 1575072

// ---- output layout (fp32 elems) ----
#define OUT_POL 0
#define OUT_QV  24576
#define OUT_EO  25344

#define SCALE_ATTN 0.17677669529663689f  // 1/sqrt(32)

// Phase fence: keeps the compiler from hoisting later phases' weight loads
// across __syncthreads (r17 lesson: VGPR 256 + spill).
#define PHASE_FENCE() __builtin_amdgcn_sched_barrier(0)

// r21 cdot8 (PROVEN WIN): cluster-coalesced weight dot. c=t>>2, o=(t&3)*4:
// each 4-lane cluster owns one output column and reads 16 CONSECUTIVE floats
// of W-row c per chunk -> 16 cache lines per wave-load vs 64 for the
// per-lane-row layout (front 40.9 -> ~33, total -8us). These phases are
// L1-line-transaction bound (TLP/balance/conflict fixes all null r19/r20).
static __device__ __forceinline__ void cdot8(
    const float* __restrict__ wrow, int o,   // o = (t&3)*4
    const float* __restrict__ x0, const float* __restrict__ x1,
    const float* __restrict__ x2, const float* __restrict__ x3,
    float* __restrict__ accs)
{
  float4 wf[8];
  #pragma unroll
  for (int ch = 0; ch < 8; ++ch)
    wf[ch] = *(const float4*)&wrow[ch * 16 + o];
  #pragma unroll
  for (int r = 0; r < 4; ++r) {
    const float* xr = (r == 0) ? x0 : (r == 1) ? x1 : (r == 2) ? x2 : x3;
    float ax = 0.f, ay = 0.f, az = 0.f, aw = 0.f;
    #pragma unroll
    for (int ch = 0; ch < 8; ++ch) {
      float4 x = *(const float4*)&xr[ch * 16 + o];
      ax = fmaf(x.x, wf[ch].x, ax); ay = fmaf(x.y, wf[ch].y, ay);
      az = fmaf(x.z, wf[ch].z, az); aw = fmaf(x.w, wf[ch].w, aw);
    }
    accs[r] += (ax + ay) + (az + aw);
  }
}

// 2-chunk (32-float) variant for K=160's tail region.
static __device__ __forceinline__ void cdot2(
    const float* __restrict__ wrow, int o,
    const float* __restrict__ x0, const float* __restrict__ x1,
    const float* __restrict__ x2, const float* __restrict__ x3,
    float* __restrict__ accs)
{
  float4 wf[2];
  #pragma unroll
  for (int ch = 0; ch < 2; ++ch)
    wf[ch] = *(const float4*)&wrow[ch * 16 + o];
  #pragma unroll
  for (int r = 0; r < 4; ++r) {
    const float* xr = (r == 0) ? x0 : (r == 1) ? x1 : (r == 2) ? x2 : x3;
    float ax = 0.f, ay = 0.f, az = 0.f, aw = 0.f;
    #pragma unroll
    for (int ch = 0; ch < 2; ++ch) {
      float4 x = *(const float4*)&xr[ch * 16 + o];
      ax = fmaf(x.x, wf[ch].x, ax); ay = fmaf(x.y, wf[ch].y, ay);
      az = fmaf(x.z, wf[ch].z, az); aw = fmaf(x.w, wf[ch].w, aw);
    }
    accs[r] += (ax + ay) + (az + aw);
  }
}

// ================================================================
// K12ws (r23 exact): weight-stationary front, 4 rows/block, grid 384,
// 512 threads, cluster-coalesced weight access. Block 0 zeroes
// out[OUT_QV..+768) for the epi's atomic q_values accumulation.
// Blocks 0..191   (E): obs -> eo -> x_e -> qkv_e
// Blocks 192..383 (A): obs -> L1 -> L2 -> L3/pol -> ea -> x_a -> qkv_a
// ================================================================
__global__ __launch_bounds__(512, 1) void k12ws_front(
    const float* __restrict__ obs,
    const float* __restrict__ aw1, const float* __restrict__ ab1,
    const float* __restrict__ aw2, const float* __restrict__ ab2,
    const float* __restrict__ aw3, const float* __restrict__ ab3,
    const float* __restrict__ eow, const float* __restrict__ eob,
    const float* __restrict__ eaw, const float* __restrict__ eab,
    const float* __restrict__ riw, const float* __restrict__ rib,
    const float* __restrict__ miw, const float* __restrict__ mib,
    float* __restrict__ out, float* __restrict__ ws)
{
  __shared__ float sA[4][256];   // A: h1, then ea in [0..128)  | E: eo
  __shared__ float sB[4][160];   // A: [obs | pol]              | E: obs
  __shared__ float sC[4][128];   // A: h2, then x_a             | E: x_e
  const int t  = threadIdx.x;
  const int bx = blockIdx.x;
  const bool isE = (bx < 192);
  const int r0 = (isE ? bx : bx - 192) * 4;

  const int c  = t >> 2;        // out-col 0..127 (one per 4-lane cluster)
  const int o  = (t & 3) * 4;   // 4-float k-slice within each 16-float chunk
  const bool q0 = (t & 3) == 0;

  if (bx == 0) {                // zero q_values accumulator (768 floats)
    for (int idx = t; idx < 768; idx += 512) out[OUT_QV + idx] = 0.f;
  }

  { // stage obs: 512 floats, 512 threads (coalesced)
    int ri = t >> 7, k = t & 127;
    sB[ri][k] = obs[(r0 + ri) * 128 + k];
  }
  __syncthreads();
  PHASE_FENCE();

  if (isE) {
    { // ---- eo ----
      float accs[4] = {0.f, 0.f, 0.f, 0.f};
      cdot8(eow + (size_t)c * 128, o,
            sB[0], sB[1], sB[2], sB[3], accs);
      const float bias = eob[c];
      #pragma unroll
      for (int r = 0; r < 4; ++r) {
        float acc = accs[r];
        acc += __shfl_xor(acc, 1);
        acc += __shfl_xor(acc, 2);
        if (q0) {
          float v = acc + bias;
          sA[r][c] = v;
          out[OUT_EO + (r0 + r) * 128 + c] = v;
        }
      }
    }
    __syncthreads();
    PHASE_FENCE();
    { // ---- x_e ----
      float accs[4] = {0.f, 0.f, 0.f, 0.f};
      cdot8(riw + (size_t)c * 128, o,
            sA[0], sA[1], sA[2], sA[3], accs);
      const float bias = rib[c];
      #pragma unroll
      for (int r = 0; r < 4; ++r) {
        float acc = accs[r];
        acc += __shfl_xor(acc, 1);
        acc += __shfl_xor(acc, 2);
        if (q0) {
          float v = fmaxf(acc + bias, 0.f);
          sC[r][c] = v;
          ws[OFF_XE + (r0 + r) * 128 + c] = v;
        }
      }
    }
    __syncthreads();
    PHASE_FENCE();
    // ---- qkv_e (3 col-groups) ----
    #pragma unroll 1
    for (int g = 0; g < 3; ++g) {
      float accs[4] = {0.f, 0.f, 0.f, 0.f};
      cdot8(miw + (size_t)(g * 128 + c) * 128, o,
            sC[0], sC[1], sC[2], sC[3], accs);
      const float bias = mib[g * 128 + c];
      #pragma unroll
      for (int r = 0; r < 4; ++r) {
        float acc = accs[r];
        acc += __shfl_xor(acc, 1);
        acc += __shfl_xor(acc, 2);
        if (q0)
          ws[OFF_QKVE + (size_t)(r0 + r) * 384 + g * 128 + c] = acc + bias;
      }
    }
  } else {
    // ---- L1 (2 col-groups) ----
    #pragma unroll 1
    for (int g = 0; g < 2; ++g) {
      float accs[4] = {0.f, 0.f, 0.f, 0.f};
      cdot8(aw1 + (size_t)(g * 128 + c) * 128, o,
            sB[0], sB[1], sB[2], sB[3], accs);
      const float bias = ab1[g * 128 + c];
      #pragma unroll
      for (int r = 0; r < 4; ++r) {
        float acc = accs[r];
        acc += __shfl_xor(acc, 1);
        acc += __shfl_xor(acc, 2);
        if (q0) sA[r][g * 128 + c] = lrelu(acc + bias);
      }
    }
    __syncthreads();
    PHASE_FENCE();
    { // ---- L2 (K=256: two 128-halves, serial cdot8 pair) ----
      float accs[4] = {0.f, 0.f, 0.f, 0.f};
      cdot8(aw2 + (size_t)c * 256, o,
            &sA[0][0], &sA[1][0], &sA[2][0], &sA[3][0], accs);
      cdot8(aw2 + (size_t)c * 256 + 128, o,
            &sA[0][128], &sA[1][128], &sA[2][128], &sA[3][128], accs);
      const float bias = ab2[c];
      #pragma unroll
      for (int r = 0; r < 4; ++r) {
        float acc = accs[r];
        acc += __shfl_xor(acc, 1);
        acc += __shfl_xor(acc, 2);
        if (q0) sC[r][c] = lrelu(acc + bias);
      }
    }
    __syncthreads();
    PHASE_FENCE();
    // ---- L3 + GELU (threads 0..127: 32 cols x 4 q) ----
    if (t < 128) {
      const int c2 = t >> 2;
      float accs[4] = {0.f, 0.f, 0.f, 0.f};
      cdot8(aw3 + (size_t)c2 * 128, o,
            sC[0], sC[1], sC[2], sC[3], accs);
      const float bias = ab3[c2];
      #pragma unroll
      for (int r = 0; r < 4; ++r) {
        float acc = accs[r];
        acc += __shfl_xor(acc, 1);
        acc += __shfl_xor(acc, 2);
        if ((t & 3) == 0) {
          float a = acc + bias;
          float g = 0.5f * a * (1.f + erff(a * 0.70710678118654752f));
          sB[r][128 + c2] = g;
          out[OUT_POL + (r0 + r) * 32 + c2] = g;
        }
      }
    }
    __syncthreads();
    PHASE_FENCE();
    { // ---- ea (K=160: 8 chunks over obs + 2 chunks over pol) ----
      float accs[4] = {0.f, 0.f, 0.f, 0.f};
      const float* wb = eaw + (size_t)c * 160;
      cdot8(wb, o, sB[0], sB[1], sB[2], sB[3], accs);
      cdot2(wb + 128, o,
            &sB[0][128], &sB[1][128], &sB[2][128], &sB[3][128], accs);
      const float bias = eab[c];
      #pragma unroll
      for (int r = 0; r < 4; ++r) {
        float acc = accs[r];
        acc += __shfl_xor(acc, 1);
        acc += __shfl_xor(acc, 2);
        if (q0) sA[r][c] = acc + bias;
      }
    }
    __syncthreads();
    PHASE_FENCE();
    { // ---- x_a ----
      float accs[4] = {0.f, 0.f, 0.f, 0.f};
      cdot8(riw + (size_t)c * 128, o,
            sA[0], sA[1], sA[2], sA[3], accs);
      const float bias = rib[c];
      #pragma unroll
      for (int r = 0; r < 4; ++r) {
        float acc = accs[r];
        acc += __shfl_xor(acc, 1);
        acc += __shfl_xor(acc, 2);
        if (q0) {
          float v = fmaxf(acc + bias, 0.f);
          sC[r][c] = v;
          ws[OFF_XA + (r0 + r) * 128 + c] = v;
        }
      }
    }
    __syncthreads();
    PHASE_FENCE();
    // ---- qkv_a (3 col-groups) ----
    #pragma unroll 1
    for (int g = 0; g < 3; ++g) {
      float accs[4] = {0.f, 0.f, 0.f, 0.f};
      cdot8(miw + (size_t)(g * 128 + c) * 128, o,
            sC[0], sC[1], sC[2], sC[3], accs);
      const float bias = mib[g * 128 + c];
      #pragma unroll
      for (int r = 0; r < 4; ++r) {
        float acc = accs[r];
        acc += __shfl_xor(acc, 1);
        acc += __shfl_xor(acc, 2);
        if (q0)
          ws[OFF_QKVA + (size_t)(r0 + r) * 384 + g * 128 + c] = acc + bias;
      }
    }
  }
}

// ================================================================
// K356 (r24 exact): fused attention, float4-vectorized staging.
// ================================================================
__global__ __launch_bounds__(256) void k356_attn(float* __restrict__ ws)
{
  __shared__ __align__(16) union {
    struct { float Qs[16 * 36]; float KsT[32 * 68]; float VsT[32 * 68]; float Ss[16 * 68]; } e;
    struct { float Qb[48 * 33]; float Ka[96 * 33]; float Va[96 * 36]; float Ss[48 * 97]; float rinv[48]; } a;
  } su;
  const int t  = threadIdx.x;
  const int bx = blockIdx.x;

  if (bx < 768) {
    const int l0 = (bx % 48) * 16, h = (bx / 48) & 3, sp = bx / 192;
    const float* qkve = ws + OFF_QKVE;

    // Q: 512 floats = 128 float4; threads 0..127 take one each.
    if (t < 128) {
      int ql = t >> 3, d4 = (t & 7) * 4;
      float4 q4 = *(const float4*)&qkve[(size_t)(l0 + ql) * 384 + h * 32 + d4];
      *(float4*)&su.e.Qs[ql * 36 + d4] = q4;   // (ql*36+d4)*4B is 16B-aligned
    }
    __syncthreads();

    const int l = t >> 4, j = t & 15, c0 = j * 4;
    float q[32];
    #pragma unroll
    for (int dd = 0; dd < 8; ++dd) {
      float4 qq = *(const float4*)&su.e.Qs[l * 36 + dd * 4];
      q[dd*4+0] = qq.x; q[dd*4+1] = qq.y; q[dd*4+2] = qq.z; q[dd*4+3] = qq.w;
    }
    float o0 = 0.f, o1 = 0.f, dsum = 0.f;

    for (int mt = sp * 3; mt < sp * 3 + 3; ++mt) {
      const int m0 = mt * 64;
      __syncthreads();
      // K/V tile: 2048 floats each = 512 float4; 2 float4/thread each.
      #pragma unroll
      for (int j2 = 0; j2 < 2; ++j2) {
        int f4 = t + j2 * 256;               // 0..511
        int i = f4 >> 3, d4 = (f4 & 7) * 4;
        const float* src = qkve + (size_t)(m0 + i) * 384 + h * 32 + d4;
        float4 kk = *(const float4*)&src[128];
        float4 vv = *(const float4*)&src[256];
        su.e.KsT[(d4+0) * 68 + i] = kk.x;
        su.e.KsT[(d4+1) * 68 + i] = kk.y;
        su.e.KsT[(d4+2) * 68 + i] = kk.z;
        su.e.KsT[(d4+3) * 68 + i] = kk.w;
        su.e.VsT[(d4+0) * 68 + i] = vv.x;
        su.e.VsT[(d4+1) * 68 + i] = vv.y;
        su.e.VsT[(d4+2) * 68 + i] = vv.z;
        su.e.VsT[(d4+3) * 68 + i] = vv.w;
      }
      __syncthreads();

      float s0 = 0.f, s1 = 0.f, s2 = 0.f, s3 = 0.f;
      #pragma unroll
      for (int d = 0; d < 32; ++d) {
        float4 kk = *(const float4*)&su.e.KsT[d * 68 + c0];
        s0 = fmaf(q[d], kk.x, s0); s1 = fmaf(q[d], kk.y, s1);
        s2 = fmaf(q[d], kk.z, s2); s3 = fmaf(q[d], kk.w, s3);
      }
      s0 = expf(s0 * SCALE_ATTN); s1 = expf(s1 * SCALE_ATTN);
      s2 = expf(s2 * SCALE_ATTN); s3 = expf(s3 * SCALE_ATTN);
      float4 sv; sv.x = s0; sv.y = s1; sv.z = s2; sv.w = s3;
      *(float4*)&su.e.Ss[l * 68 + c0] = sv;
      float psum = (s0 + s1) + (s2 + s3);
      psum += __shfl_xor(psum, 1); psum += __shfl_xor(psum, 2);
      psum += __shfl_xor(psum, 4); psum += __shfl_xor(psum, 8);
      dsum += psum;

      float t0x=0.f,t0y=0.f,t0z=0.f,t0w=0.f, t1x=0.f,t1y=0.f,t1z=0.f,t1w=0.f;
      #pragma unroll
      for (int k4 = 0; k4 < 16; ++k4) {
        float4 p  = *(const float4*)&su.e.Ss[l * 68 + k4 * 4];
        float4 va = *(const float4*)&su.e.VsT[j * 68 + k4 * 4];
        float4 vb = *(const float4*)&su.e.VsT[(j + 16) * 68 + k4 * 4];
        t0x = fmaf(p.x, va.x, t0x); t0y = fmaf(p.y, va.y, t0y);
        t0z = fmaf(p.z, va.z, t0z); t0w = fmaf(p.w, va.w, t0w);
        t1x = fmaf(p.x, vb.x, t1x); t1y = fmaf(p.y, vb.y, t1y);
        t1z = fmaf(p.z, vb.z, t1z); t1w = fmaf(p.w, vb.w, t1w);
      }
      o0 += (t0x + t0y) + (t0z + t0w);
      o1 += (t1x + t1y) + (t1z + t1w);
    }

    float* aop = ws + OFF_AOP + (size_t)sp * 98304;
    aop[(size_t)(l0 + l) * 128 + h * 32 + j]      = o0;
    aop[(size_t)(l0 + l) * 128 + h * 32 + j + 16] = o1;
    if (j == 0) ws[OFF_DEN + sp * 3072 + (l0 + l) * 4 + h] = dsum;
  } else {
    const int z  = bx - 768;
    const int j1 = z >> 3;
    const int h  = (z & 7) >> 1, rb = z & 1;
    const int jj = j1 + 1;
    const float* qkva = ws + OFF_QKVA;

    // Ka/Va: 3072 floats each = 768 float4; 3 float4/thread each.
    for (int f4 = t; f4 < 768; f4 += 256) {
      int ml = f4 >> 3, d4 = (f4 & 7) * 4;
      int bp = ml >> 1, spar = ml & 1;
      int ag = spar ? jj : (jj - 1);
      const float* src = qkva + (size_t)(bp * 16 + ag) * 384 + h * 32 + d4;
      float4 kk = *(const float4*)&src[128];
      float4 vv = *(const float4*)&src[256];
      su.a.Ka[ml * 33 + d4 + 0] = kk.x;
      su.a.Ka[ml * 33 + d4 + 1] = kk.y;
      su.a.Ka[ml * 33 + d4 + 2] = kk.z;
      su.a.Ka[ml * 33 + d4 + 3] = kk.w;
      *(float4*)&su.a.Va[ml * 36 + d4] = vv;   // stride 36: 16B-aligned
    }
    // Qb: 1536 floats = 384 float4.
    for (int f4 = t; f4 < 384; f4 += 256) {
      int ql = f4 >> 3, d4 = (f4 & 7) * 4;
      int Lb = rb * 48 + ql;
      int b = Lb >> 1, s = Lb & 1;
      int ag = s ? jj : (jj - 1);
      float4 q4 = *(const float4*)&qkva[(size_t)(b * 16 + ag) * 384 + h * 32 + d4];
      su.a.Qb[ql * 33 + d4 + 0] = q4.x;
      su.a.Qb[ql * 33 + d4 + 1] = q4.y;
      su.a.Qb[ql * 33 + d4 + 2] = q4.z;
      su.a.Qb[ql * 33 + d4 + 3] = q4.w;
    }
    __syncthreads();

    {
      const int tl = (t >> 4) * 3, tm = (t & 15) * 6;
      float acc[3][6] = {{0.f}};
      #pragma unroll
      for (int d = 0; d < 32; ++d) {
        float qv[3], kv[6];
        #pragma unroll
        for (int r = 0; r < 3; ++r) qv[r] = su.a.Qb[(tl + r) * 33 + d];
        #pragma unroll
        for (int c = 0; c < 6; ++c) kv[c] = su.a.Ka[(tm + c) * 33 + d];
        #pragma unroll
        for (int r = 0; r < 3; ++r)
          #pragma unroll
          for (int c = 0; c < 6; ++c) acc[r][c] = fmaf(qv[r], kv[c], acc[r][c]);
      }
      const float wj = (float)jj, wnj = (float)(16 - jj);
      float rs[3] = {0.f, 0.f, 0.f};
      #pragma unroll
      for (int r = 0; r < 3; ++r)
        #pragma unroll
        for (int c = 0; c < 6; ++c) {
          float w = ((tm + c) & 1) ? wj : wnj;
          float p = w * expf(acc[r][c] * SCALE_ATTN);
          su.a.Ss[(tl + r) * 97 + tm + c] = p;
          rs[r] += p;
        }
      #pragma unroll
      for (int r = 0; r < 3; ++r) {
        rs[r] += __shfl_xor(rs[r], 1); rs[r] += __shfl_xor(rs[r], 2);
        rs[r] += __shfl_xor(rs[r], 4); rs[r] += __shfl_xor(rs[r], 8);
      }
      if ((t & 15) == 0) {
        su.a.rinv[tl + 0] = 1.f / rs[0];
        su.a.rinv[tl + 1] = 1.f / rs[1];
        su.a.rinv[tl + 2] = 1.f / rs[2];
      }
    }
    __syncthreads();

    if (t < 192) {
      const int l0 = (t >> 3) * 2, d0 = (t & 7) * 4;
      float a0x=0.f,a0y=0.f,a0z=0.f,a0w=0.f, a1x=0.f,a1y=0.f,a1z=0.f,a1w=0.f;
      for (int m = 0; m < 96; ++m) {
        float p0 = su.a.Ss[l0 * 97 + m], p1 = su.a.Ss[(l0 + 1) * 97 + m];
        float4 v = *(const float4*)&su.a.Va[m * 36 + d0];
        a0x = fmaf(p0, v.x, a0x); a0y = fmaf(p0, v.y, a0y);
        a0z = fmaf(p0, v.z, a0z); a0w = fmaf(p0, v.w, a0w);
        a1x = fmaf(p1, v.x, a1x); a1y = fmaf(p1, v.y, a1y);
        a1z = fmaf(p1, v.z, a1z); a1w = fmaf(p1, v.w, a1w);
      }
      const float s0 = su.a.rinv[l0], s1 = su.a.rinv[l0 + 1];
      float* ao = ws + OFF_AOA + (size_t)(j1 * 96 + rb * 48 + l0) * 128 + h * 32 + d0;
      float4 o0; o0.x = a0x * s0; o0.y = a0y * s0; o0.z = a0z * s0; o0.w = a0w * s0;
      float4 o1; o1.x = a1x * s1; o1.y = a1y * s1; o1.z = a1z * s1; o1.w = a1w * s1;
      *(float4*)ao = o0;
      *(float4*)(ao + 128) = o1;
    }
  }
}

// ================================================================
// K7ab r25: merged epilogue — r15 dot structure + k8 atomic fold (both
// proven), staging VECTORIZED: rows_in/res were ~36 scalar 4B loads per
// thread before the first barrier (same exposed-chain pathology r24 fixed
// in attn). Now 256 float4s, one per thread: ri=t>>5, c4=(t&31)*4.
// DEN's hh=c>>5 is constant across a 4-aligned quad -> one scalar sum.
// rows_in[ri][c4] (132*ri+c4 = 0 mod 4) -> aligned vector ds_write.
// ================================================================
__global__ __launch_bounds__(256) void k7ab_epi(
    const float* __restrict__ mow, const float* __restrict__ mob,
    const float* __restrict__ roww, const float* __restrict__ robb,
    const float* __restrict__ qw,  const float* __restrict__ qb,
    float* __restrict__ ws, float* __restrict__ out)
{
  __shared__ float rows_in[8][132];
  __shared__ float res[8][132];
  __shared__ float t1s[8][132];
  __shared__ float qpart[8][4];
  const int t  = threadIdx.x;
  const int r0 = blockIdx.x * 8;

  { // staging: 8 rows x 128 cols = 256 float4, one per thread
    int ri = t >> 5, c4 = (t & 31) * 4;
    int r = r0 + ri;
    float4 aoval, x1v;
    if (r < 768) {
      float4 n0 = *(const float4*)&ws[OFF_AOP + 0*98304 + (size_t)r*128 + c4];
      float4 n1 = *(const float4*)&ws[OFF_AOP + 1*98304 + (size_t)r*128 + c4];
      float4 n2 = *(const float4*)&ws[OFF_AOP + 2*98304 + (size_t)r*128 + c4];
      float4 n3 = *(const float4*)&ws[OFF_AOP + 3*98304 + (size_t)r*128 + c4];
      int hh = c4 >> 5;
      float den = ws[OFF_DEN + 0*3072 + r*4 + hh] + ws[OFF_DEN + 1*3072 + r*4 + hh]
                + ws[OFF_DEN + 2*3072 + r*4 + hh] + ws[OFF_DEN + 3*3072 + r*4 + hh];
      float rinv = 1.f / den;
      aoval.x = ((n0.x + n1.x) + (n2.x + n3.x)) * rinv;
      aoval.y = ((n0.y + n1.y) + (n2.y + n3.y)) * rinv;
      aoval.z = ((n0.z + n1.z) + (n2.z + n3.z)) * rinv;
      aoval.w = ((n0.w + n1.w) + (n2.w + n3.w)) * rinv;
      x1v = *(const float4*)&ws[OFF_XE + (size_t)r*128 + c4];
    } else {
      int rr = r - 768;
      aoval = *(const float4*)&ws[OFF_AOA + (size_t)rr*128 + c4];
      int jx = rr / 96, l96 = rr % 96;
      int b = l96 >> 1, sa = l96 & 1;
      int ag = sa ? (jx + 1) : jx;
      x1v = *(const float4*)&ws[OFF_XA + (size_t)(b*16 + ag)*128 + c4];
    }
    *(float4*)&rows_in[ri][c4] = aoval;
    *(float4*)&res[ri][c4] = x1v;
  }

  const int c = (t & 31) | ((t >> 6) << 5);
  const int h = (t >> 5) & 1;
  __syncthreads();

  { // t1 phase (runtime-looped chunks)
    float accs[8] = {0.f,0.f,0.f,0.f,0.f,0.f,0.f,0.f};
    const float* wb = mow + c * 128 + h * 64;
    #pragma unroll 1
    for (int ch = 0; ch < 2; ++ch) {
      const float4* wp = (const float4*)(wb + ch * 32);
      float4 wf[8];
      #pragma unroll
      for (int i = 0; i < 8; ++i) wf[i] = wp[i];
      #pragma unroll
      for (int ri = 0; ri < 8; ++ri) {
        const float* xr = &rows_in[ri][h * 64 + ch * 32];
        float ax = 0.f, ay = 0.f, az = 0.f, aw = 0.f;
        #pragma unroll
        for (int i = 0; i < 8; ++i) {
          float4 x = *(const float4*)&xr[i * 4];
          ax = fmaf(x.x, wf[i].x, ax); ay = fmaf(x.y, wf[i].y, ay);
          az = fmaf(x.z, wf[i].z, az); aw = fmaf(x.w, wf[i].w, aw);
        }
        accs[ri] += (ax + ay) + (az + aw);
      }
    }
    const float bias = mob[c];
    #pragma unroll
    for (int ri = 0; ri < 8; ++ri) {
      float acc = accs[ri];
      acc += __shfl_xor(acc, 32);
      if (h == 0) t1s[ri][c] = acc + bias + res[ri][c];
    }
  }
  __syncthreads();

  { // ctx + qv phase
    float accs[8] = {0.f,0.f,0.f,0.f,0.f,0.f,0.f,0.f};
    const float* wb = roww + c * 128 + h * 64;
    #pragma unroll 1
    for (int ch = 0; ch < 2; ++ch) {
      const float4* wp = (const float4*)(wb + ch * 32);
      float4 wf[8];
      #pragma unroll
      for (int i = 0; i < 8; ++i) wf[i] = wp[i];
      #pragma unroll
      for (int ri = 0; ri < 8; ++ri) {
        const float* xr = &t1s[ri][h * 64 + ch * 32];
        float ax = 0.f, ay = 0.f, az = 0.f, aw = 0.f;
        #pragma unroll
        for (int i = 0; i < 8; ++i) {
          float4 x = *(const float4*)&xr[i * 4];
          ax = fmaf(x.x, wf[i].x, ax); ay = fmaf(x.y, wf[i].y, ay);
          az = fmaf(x.z, wf[i].z, az); aw = fmaf(x.w, wf[i].w, aw);
        }
        accs[ri] += (ax + ay) + (az + aw);
      }
    }
    const float bias = robb[c];
    const float qwc  = qw[c];
    #pragma unroll
    for (int ri = 0; ri < 8; ++ri) {
      float acc = accs[ri];
      acc += __shfl_xor(acc, 32);
      float ctx = fmaxf(acc + bias, 0.f);
      float p = (h == 0) ? qwc * ctx : 0.f;
      p += __shfl_xor(p, 1);  p += __shfl_xor(p, 2);  p += __shfl_xor(p, 4);
      p += __shfl_xor(p, 8);  p += __shfl_xor(p, 16); p += __shfl_xor(p, 32);
      if ((t & 63) == 0) qpart[ri][t >> 6] = p;
    }
  }
  __syncthreads();

  if (t < 8) {
    float qv = (qpart[t][0] + qpart[t][1]) + (qpart[t][2] + qpart[t][3]) + qb[0];
    int r = r0 + t;
    if (r < 768) {
      atomicAdd(&out[OUT_QV + r], qv);
    } else {
      int rr = r - 768;
      int jx = rr / 96, l96 = rr % 96;
      int b = l96 >> 1, sa = l96 & 1;
      int jj = jx + 1;
      // s==0 row feeds i >= jj ; s==1 row feeds i < jj
      int ibeg = sa ? 0 : jj;
      int iend = sa ? jj : 16;
      for (int i = ibeg; i < iend; ++i)
        atomicAdd(&out[OUT_QV + b * 16 + i], qv);
    }
  }
}

// ================================================================
extern "C" void kernel_launch(void* const* d_in, const int* in_sizes, int n_in,
                              void* d_out, int out_size, void* d_ws, size_t ws_size,
                              hipStream_t stream)
{
  (void)in_sizes; (void)n_in; (void)out_size;
  if (ws_size < (size_t)WS_FLOATS * 4) return;

  const float* obs = (const float*)d_in[0];
  const float* aw1 = (const float*)d_in[1];
  const float* ab1 = (const float*)d_in[2];
  const float* aw2 = (const float*)d_in[3];
  const float* ab2 = (const float*)d_in[4];
  const float* aw3 = (const float*)d_in[5];
  const float* ab3 = (const float*)d_in[6];
  const float* eow = (const float*)d_in[7];
  const float* eob = (const float*)d_in[8];
  const float* eaw = (const float*)d_in[9];
  const float* eab = (const float*)d_in[10];
  const float* riw = (const float*)d_in[11];
  const float* rib = (const float*)d_in[12];
  const float* roww= (const float*)d_in[13];
  const float* robb= (const float*)d_in[14];
  const float* miw = (const float*)d_in[15];
  const float* mib = (const float*)d_in[16];
  const float* mow = (const float*)d_in[17];
  const float* mob = (const float*)d_in[18];
  const float* qw  = (const float*)d_in[19];
  const float* qb  = (const float*)d_in[20];

  float* out = (float*)d_out;
  float* ws  = (float*)d_ws;

  k12ws_front<<<dim3(384), dim3(512), 0, stream>>>(obs, aw1, ab1, aw2, ab2, aw3, ab3,
                                                   eow, eob, eaw, eab, riw, rib, miw, mib,
                                                   out, ws);
  k356_attn<<<dim3(888), dim3(256), 0, stream>>>(ws);
  k7ab_epi<<<dim3(276), dim3(256), 0, stream>>>(mow, mob, roww, robb, qw, qb, ws, out);
}

// Round 11
// 152.300 us; speedup vs baseline: 1.1076x; 1.0122x over previous
//
#include <hip/hip_runtime.h>
#include <math.h>

static __device__ __forceinline__ float lrelu(float x){ return x > 0.f ? x : 0.01f * x; }

// ---- workspace layout (float offsets) ----
#define OFF_XE    196608
#define OFF_XA    294912
#define OFF_QKVE  393216
#define OFF_QKVA  688128
#define OFF_AOP   983040    // 4 splits * 768*128
#define OFF_DEN   1376256   // 4 splits * 768*4
#define OFF_AOA   1388544   // 15*96*128
#define WS_FLOATS 1575072

// ---- output layout (fp32 elems) ----
#define OUT_POL 0
#define OUT_QV  24576
#define OUT_EO  25344

#define SCALE_ATTN 0.17677669529663689f  // 1/sqrt(32)

// Phase fence: keeps the compiler from hoisting later phases' weight loads
// across __syncthreads (r17 lesson: VGPR 256 + spill).
#define PHASE_FENCE() __builtin_amdgcn_sched_barrier(0)

// r21 cdot8 (PROVEN WIN): cluster-coalesced weight dot. c=t>>2, o=(t&3)*4:
// each 4-lane cluster owns one output column and reads 16 CONSECUTIVE floats
// of W-row c per chunk -> 16 cache lines per wave-load vs 64 for the
// per-lane-row layout (front 40.9 -> ~33, total -8us). These phases are
// L1-line-transaction bound (TLP/balance/conflict fixes all null r19/r20).
static __device__ __forceinline__ void cdot8(
    const float* __restrict__ wrow, int o,   // o = (t&3)*4
    const float* __restrict__ x0, const float* __restrict__ x1,
    const float* __restrict__ x2, const float* __restrict__ x3,
    float* __restrict__ accs)
{
  float4 wf[8];
  #pragma unroll
  for (int ch = 0; ch < 8; ++ch)
    wf[ch] = *(const float4*)&wrow[ch * 16 + o];
  #pragma unroll
  for (int r = 0; r < 4; ++r) {
    const float* xr = (r == 0) ? x0 : (r == 1) ? x1 : (r == 2) ? x2 : x3;
    float ax = 0.f, ay = 0.f, az = 0.f, aw = 0.f;
    #pragma unroll
    for (int ch = 0; ch < 8; ++ch) {
      float4 x = *(const float4*)&xr[ch * 16 + o];
      ax = fmaf(x.x, wf[ch].x, ax); ay = fmaf(x.y, wf[ch].y, ay);
      az = fmaf(x.z, wf[ch].z, az); aw = fmaf(x.w, wf[ch].w, aw);
    }
    accs[r] += (ax + ay) + (az + aw);
  }
}

// 2-chunk (32-float) variant for K=160's tail region.
static __device__ __forceinline__ void cdot2(
    const float* __restrict__ wrow, int o,
    const float* __restrict__ x0, const float* __restrict__ x1,
    const float* __restrict__ x2, const float* __restrict__ x3,
    float* __restrict__ accs)
{
  float4 wf[2];
  #pragma unroll
  for (int ch = 0; ch < 2; ++ch)
    wf[ch] = *(const float4*)&wrow[ch * 16 + o];
  #pragma unroll
  for (int r = 0; r < 4; ++r) {
    const float* xr = (r == 0) ? x0 : (r == 1) ? x1 : (r == 2) ? x2 : x3;
    float ax = 0.f, ay = 0.f, az = 0.f, aw = 0.f;
    #pragma unroll
    for (int ch = 0; ch < 2; ++ch) {
      float4 x = *(const float4*)&xr[ch * 16 + o];
      ax = fmaf(x.x, wf[ch].x, ax); ay = fmaf(x.y, wf[ch].y, ay);
      az = fmaf(x.z, wf[ch].z, az); aw = fmaf(x.w, wf[ch].w, aw);
    }
    accs[r] += (ax + ay) + (az + aw);
  }
}

// ================================================================
// K12ws (r23 exact): weight-stationary front, 4 rows/block, grid 384,
// 512 threads, cluster-coalesced weight access. Block 0 zeroes
// out[OUT_QV..+768) for the epi's atomic q_values accumulation.
// Blocks 0..191   (E): obs -> eo -> x_e -> qkv_e
// Blocks 192..383 (A): obs -> L1 -> L2 -> L3/pol -> ea -> x_a -> qkv_a
// ================================================================
__global__ __launch_bounds__(512, 1) void k12ws_front(
    const float* __restrict__ obs,
    const float* __restrict__ aw1, const float* __restrict__ ab1,
    const float* __restrict__ aw2, const float* __restrict__ ab2,
    const float* __restrict__ aw3, const float* __restrict__ ab3,
    const float* __restrict__ eow, const float* __restrict__ eob,
    const float* __restrict__ eaw, const float* __restrict__ eab,
    const float* __restrict__ riw, const float* __restrict__ rib,
    const float* __restrict__ miw, const float* __restrict__ mib,
    float* __restrict__ out, float* __restrict__ ws)
{
  __shared__ float sA[4][256];   // A: h1, then ea in [0..128)  | E: eo
  __shared__ float sB[4][160];   // A: [obs | pol]              | E: obs
  __shared__ float sC[4][128];   // A: h2, then x_a             | E: x_e
  const int t  = threadIdx.x;
  const int bx = blockIdx.x;
  const bool isE = (bx < 192);
  const int r0 = (isE ? bx : bx - 192) * 4;

  const int c  = t >> 2;        // out-col 0..127 (one per 4-lane cluster)
  const int o  = (t & 3) * 4;   // 4-float k-slice within each 16-float chunk
  const bool q0 = (t & 3) == 0;

  if (bx == 0) {                // zero q_values accumulator (768 floats)
    for (int idx = t; idx < 768; idx += 512) out[OUT_QV + idx] = 0.f;
  }

  { // stage obs: 512 floats, 512 threads (coalesced)
    int ri = t >> 7, k = t & 127;
    sB[ri][k] = obs[(r0 + ri) * 128 + k];
  }
  __syncthreads();
  PHASE_FENCE();

  if (isE) {
    { // ---- eo ----
      float accs[4] = {0.f, 0.f, 0.f, 0.f};
      cdot8(eow + (size_t)c * 128, o,
            sB[0], sB[1], sB[2], sB[3], accs);
      const float bias = eob[c];
      #pragma unroll
      for (int r = 0; r < 4; ++r) {
        float acc = accs[r];
        acc += __shfl_xor(acc, 1);
        acc += __shfl_xor(acc, 2);
        if (q0) {
          float v = acc + bias;
          sA[r][c] = v;
          out[OUT_EO + (r0 + r) * 128 + c] = v;
        }
      }
    }
    __syncthreads();
    PHASE_FENCE();
    { // ---- x_e ----
      float accs[4] = {0.f, 0.f, 0.f, 0.f};
      cdot8(riw + (size_t)c * 128, o,
            sA[0], sA[1], sA[2], sA[3], accs);
      const float bias = rib[c];
      #pragma unroll
      for (int r = 0; r < 4; ++r) {
        float acc = accs[r];
        acc += __shfl_xor(acc, 1);
        acc += __shfl_xor(acc, 2);
        if (q0) {
          float v = fmaxf(acc + bias, 0.f);
          sC[r][c] = v;
          ws[OFF_XE + (r0 + r) * 128 + c] = v;
        }
      }
    }
    __syncthreads();
    PHASE_FENCE();
    // ---- qkv_e (3 col-groups) ----
    #pragma unroll 1
    for (int g = 0; g < 3; ++g) {
      float accs[4] = {0.f, 0.f, 0.f, 0.f};
      cdot8(miw + (size_t)(g * 128 + c) * 128, o,
            sC[0], sC[1], sC[2], sC[3], accs);
      const float bias = mib[g * 128 + c];
      #pragma unroll
      for (int r = 0; r < 4; ++r) {
        float acc = accs[r];
        acc += __shfl_xor(acc, 1);
        acc += __shfl_xor(acc, 2);
        if (q0)
          ws[OFF_QKVE + (size_t)(r0 + r) * 384 + g * 128 + c] = acc + bias;
      }
    }
  } else {
    // ---- L1 (2 col-groups) ----
    #pragma unroll 1
    for (int g = 0; g < 2; ++g) {
      float accs[4] = {0.f, 0.f, 0.f, 0.f};
      cdot8(aw1 + (size_t)(g * 128 + c) * 128, o,
            sB[0], sB[1], sB[2], sB[3], accs);
      const float bias = ab1[g * 128 + c];
      #pragma unroll
      for (int r = 0; r < 4; ++r) {
        float acc = accs[r];
        acc += __shfl_xor(acc, 1);
        acc += __shfl_xor(acc, 2);
        if (q0) sA[r][g * 128 + c] = lrelu(acc + bias);
      }
    }
    __syncthreads();
    PHASE_FENCE();
    { // ---- L2 (K=256: two 128-halves, serial cdot8 pair) ----
      float accs[4] = {0.f, 0.f, 0.f, 0.f};
      cdot8(aw2 + (size_t)c * 256, o,
            &sA[0][0], &sA[1][0], &sA[2][0], &sA[3][0], accs);
      cdot8(aw2 + (size_t)c * 256 + 128, o,
            &sA[0][128], &sA[1][128], &sA[2][128], &sA[3][128], accs);
      const float bias = ab2[c];
      #pragma unroll
      for (int r = 0; r < 4; ++r) {
        float acc = accs[r];
        acc += __shfl_xor(acc, 1);
        acc += __shfl_xor(acc, 2);
        if (q0) sC[r][c] = lrelu(acc + bias);
      }
    }
    __syncthreads();
    PHASE_FENCE();
    // ---- L3 + GELU (threads 0..127: 32 cols x 4 q) ----
    if (t < 128) {
      const int c2 = t >> 2;
      float accs[4] = {0.f, 0.f, 0.f, 0.f};
      cdot8(aw3 + (size_t)c2 * 128, o,
            sC[0], sC[1], sC[2], sC[3], accs);
      const float bias = ab3[c2];
      #pragma unroll
      for (int r = 0; r < 4; ++r) {
        float acc = accs[r];
        acc += __shfl_xor(acc, 1);
        acc += __shfl_xor(acc, 2);
        if ((t & 3) == 0) {
          float a = acc + bias;
          float g = 0.5f * a * (1.f + erff(a * 0.70710678118654752f));
          sB[r][128 + c2] = g;
          out[OUT_POL + (r0 + r) * 32 + c2] = g;
        }
      }
    }
    __syncthreads();
    PHASE_FENCE();
    { // ---- ea (K=160: 8 chunks over obs + 2 chunks over pol) ----
      float accs[4] = {0.f, 0.f, 0.f, 0.f};
      const float* wb = eaw + (size_t)c * 160;
      cdot8(wb, o, sB[0], sB[1], sB[2], sB[3], accs);
      cdot2(wb + 128, o,
            &sB[0][128], &sB[1][128], &sB[2][128], &sB[3][128], accs);
      const float bias = eab[c];
      #pragma unroll
      for (int r = 0; r < 4; ++r) {
        float acc = accs[r];
        acc += __shfl_xor(acc, 1);
        acc += __shfl_xor(acc, 2);
        if (q0) sA[r][c] = acc + bias;
      }
    }
    __syncthreads();
    PHASE_FENCE();
    { // ---- x_a ----
      float accs[4] = {0.f, 0.f, 0.f, 0.f};
      cdot8(riw + (size_t)c * 128, o,
            sA[0], sA[1], sA[2], sA[3], accs);
      const float bias = rib[c];
      #pragma unroll
      for (int r = 0; r < 4; ++r) {
        float acc = accs[r];
        acc += __shfl_xor(acc, 1);
        acc += __shfl_xor(acc, 2);
        if (q0) {
          float v = fmaxf(acc + bias, 0.f);
          sC[r][c] = v;
          ws[OFF_XA + (r0 + r) * 128 + c] = v;
        }
      }
    }
    __syncthreads();
    PHASE_FENCE();
    // ---- qkv_a (3 col-groups) ----
    #pragma unroll 1
    for (int g = 0; g < 3; ++g) {
      float accs[4] = {0.f, 0.f, 0.f, 0.f};
      cdot8(miw + (size_t)(g * 128 + c) * 128, o,
            sC[0], sC[1], sC[2], sC[3], accs);
      const float bias = mib[g * 128 + c];
      #pragma unroll
      for (int r = 0; r < 4; ++r) {
        float acc = accs[r];
        acc += __shfl_xor(acc, 1);
        acc += __shfl_xor(acc, 2);
        if (q0)
          ws[OFF_QKVA + (size_t)(r0 + r) * 384 + g * 128 + c] = acc + bias;
      }
    }
  }
}

// ================================================================
// K356 r26: fused attention. E-path adds T14 async-STAGE: K/V tile held
// in regs (2+2 float4/thread); regs->LDS at loop top; NEXT tile's global
// loads issued right after the second barrier so L2 latency hides under
// the current tile's QK/softmax/PV compute (staging was the last exposed
// serial chain — r24 vectorized it, r26 overlaps it). A-path unchanged.
// ================================================================
__global__ __launch_bounds__(256) void k356_attn(float* __restrict__ ws)
{
  __shared__ __align__(16) union {
    struct { float Qs[16 * 36]; float KsT[32 * 68]; float VsT[32 * 68]; float Ss[16 * 68]; } e;
    struct { float Qb[48 * 33]; float Ka[96 * 33]; float Va[96 * 36]; float Ss[48 * 97]; float rinv[48]; } a;
  } su;
  const int t  = threadIdx.x;
  const int bx = blockIdx.x;

  if (bx < 768) {
    const int l0 = (bx % 48) * 16, h = (bx / 48) & 3, sp = bx / 192;
    const float* qkve = ws + OFF_QKVE;

    // Q: 512 floats = 128 float4; threads 0..127 take one each.
    if (t < 128) {
      int ql = t >> 3, d4 = (t & 7) * 4;
      float4 q4 = *(const float4*)&qkve[(size_t)(l0 + ql) * 384 + h * 32 + d4];
      *(float4*)&su.e.Qs[ql * 36 + d4] = q4;   // (ql*36+d4)*4B is 16B-aligned
    }

    // T14: prefetch tile 0 K/V into regs (latency overlaps Qs barrier + q read)
    float4 kr[2], vr[2];
    {
      const int m0 = sp * 3 * 64;
      #pragma unroll
      for (int j2 = 0; j2 < 2; ++j2) {
        int f4 = t + j2 * 256;               // 0..511
        int i = f4 >> 3, d4 = (f4 & 7) * 4;
        const float* src = qkve + (size_t)(m0 + i) * 384 + h * 32 + d4;
        kr[j2] = *(const float4*)&src[128];
        vr[j2] = *(const float4*)&src[256];
      }
    }
    __syncthreads();

    const int l = t >> 4, j = t & 15, c0 = j * 4;
    float q[32];
    #pragma unroll
    for (int dd = 0; dd < 8; ++dd) {
      float4 qq = *(const float4*)&su.e.Qs[l * 36 + dd * 4];
      q[dd*4+0] = qq.x; q[dd*4+1] = qq.y; q[dd*4+2] = qq.z; q[dd*4+3] = qq.w;
    }
    float o0 = 0.f, o1 = 0.f, dsum = 0.f;

    for (int mt = sp * 3; mt < sp * 3 + 3; ++mt) {
      __syncthreads();                       // prev tile compute done with KsT/VsT
      #pragma unroll
      for (int j2 = 0; j2 < 2; ++j2) {       // staged regs -> LDS
        int f4 = t + j2 * 256;
        int i = f4 >> 3, d4 = (f4 & 7) * 4;
        su.e.KsT[(d4+0) * 68 + i] = kr[j2].x;
        su.e.KsT[(d4+1) * 68 + i] = kr[j2].y;
        su.e.KsT[(d4+2) * 68 + i] = kr[j2].z;
        su.e.KsT[(d4+3) * 68 + i] = kr[j2].w;
        su.e.VsT[(d4+0) * 68 + i] = vr[j2].x;
        su.e.VsT[(d4+1) * 68 + i] = vr[j2].y;
        su.e.VsT[(d4+2) * 68 + i] = vr[j2].z;
        su.e.VsT[(d4+3) * 68 + i] = vr[j2].w;
      }
      __syncthreads();
      if (mt + 1 < sp * 3 + 3) {             // prefetch next tile under compute
        const int m0n = (mt + 1) * 64;
        #pragma unroll
        for (int j2 = 0; j2 < 2; ++j2) {
          int f4 = t + j2 * 256;
          int i = f4 >> 3, d4 = (f4 & 7) * 4;
          const float* src = qkve + (size_t)(m0n + i) * 384 + h * 32 + d4;
          kr[j2] = *(const float4*)&src[128];
          vr[j2] = *(const float4*)&src[256];
        }
      }

      float s0 = 0.f, s1 = 0.f, s2 = 0.f, s3 = 0.f;
      #pragma unroll
      for (int d = 0; d < 32; ++d) {
        float4 kk = *(const float4*)&su.e.KsT[d * 68 + c0];
        s0 = fmaf(q[d], kk.x, s0); s1 = fmaf(q[d], kk.y, s1);
        s2 = fmaf(q[d], kk.z, s2); s3 = fmaf(q[d], kk.w, s3);
      }
      s0 = expf(s0 * SCALE_ATTN); s1 = expf(s1 * SCALE_ATTN);
      s2 = expf(s2 * SCALE_ATTN); s3 = expf(s3 * SCALE_ATTN);
      float4 sv; sv.x = s0; sv.y = s1; sv.z = s2; sv.w = s3;
      *(float4*)&su.e.Ss[l * 68 + c0] = sv;
      float psum = (s0 + s1) + (s2 + s3);
      psum += __shfl_xor(psum, 1); psum += __shfl_xor(psum, 2);
      psum += __shfl_xor(psum, 4); psum += __shfl_xor(psum, 8);
      dsum += psum;

      float t0x=0.f,t0y=0.f,t0z=0.f,t0w=0.f, t1x=0.f,t1y=0.f,t1z=0.f,t1w=0.f;
      #pragma unroll
      for (int k4 = 0; k4 < 16; ++k4) {
        float4 p  = *(const float4*)&su.e.Ss[l * 68 + k4 * 4];
        float4 va = *(const float4*)&su.e.VsT[j * 68 + k4 * 4];
        float4 vb = *(const float4*)&su.e.VsT[(j + 16) * 68 + k4 * 4];
        t0x = fmaf(p.x, va.x, t0x); t0y = fmaf(p.y, va.y, t0y);
        t0z = fmaf(p.z, va.z, t0z); t0w = fmaf(p.w, va.w, t0w);
        t1x = fmaf(p.x, vb.x, t1x); t1y = fmaf(p.y, vb.y, t1y);
        t1z = fmaf(p.z, vb.z, t1z); t1w = fmaf(p.w, vb.w, t1w);
      }
      o0 += (t0x + t0y) + (t0z + t0w);
      o1 += (t1x + t1y) + (t1z + t1w);
    }

    float* aop = ws + OFF_AOP + (size_t)sp * 98304;
    aop[(size_t)(l0 + l) * 128 + h * 32 + j]      = o0;
    aop[(size_t)(l0 + l) * 128 + h * 32 + j + 16] = o1;
    if (j == 0) ws[OFF_DEN + sp * 3072 + (l0 + l) * 4 + h] = dsum;
  } else {
    const int z  = bx - 768;
    const int j1 = z >> 3;
    const int h  = (z & 7) >> 1, rb = z & 1;
    const int jj = j1 + 1;
    const float* qkva = ws + OFF_QKVA;

    // Ka/Va: 3072 floats each = 768 float4; 3 float4/thread each.
    for (int f4 = t; f4 < 768; f4 += 256) {
      int ml = f4 >> 3, d4 = (f4 & 7) * 4;
      int bp = ml >> 1, spar = ml & 1;
      int ag = spar ? jj : (jj - 1);
      const float* src = qkva + (size_t)(bp * 16 + ag) * 384 + h * 32 + d4;
      float4 kk = *(const float4*)&src[128];
      float4 vv = *(const float4*)&src[256];
      su.a.Ka[ml * 33 + d4 + 0] = kk.x;
      su.a.Ka[ml * 33 + d4 + 1] = kk.y;
      su.a.Ka[ml * 33 + d4 + 2] = kk.z;
      su.a.Ka[ml * 33 + d4 + 3] = kk.w;
      *(float4*)&su.a.Va[ml * 36 + d4] = vv;   // stride 36: 16B-aligned
    }
    // Qb: 1536 floats = 384 float4.
    for (int f4 = t; f4 < 384; f4 += 256) {
      int ql = f4 >> 3, d4 = (f4 & 7) * 4;
      int Lb = rb * 48 + ql;
      int b = Lb >> 1, s = Lb & 1;
      int ag = s ? jj : (jj - 1);
      float4 q4 = *(const float4*)&qkva[(size_t)(b * 16 + ag) * 384 + h * 32 + d4];
      su.a.Qb[ql * 33 + d4 + 0] = q4.x;
      su.a.Qb[ql * 33 + d4 + 1] = q4.y;
      su.a.Qb[ql * 33 + d4 + 2] = q4.z;
      su.a.Qb[ql * 33 + d4 + 3] = q4.w;
    }
    __syncthreads();

    {
      const int tl = (t >> 4) * 3, tm = (t & 15) * 6;
      float acc[3][6] = {{0.f}};
      #pragma unroll
      for (int d = 0; d < 32; ++d) {
        float qv[3], kv[6];
        #pragma unroll
        for (int r = 0; r < 3; ++r) qv[r] = su.a.Qb[(tl + r) * 33 + d];
        #pragma unroll
        for (int c = 0; c < 6; ++c) kv[c] = su.a.Ka[(tm + c) * 33 + d];
        #pragma unroll
        for (int r = 0; r < 3; ++r)
          #pragma unroll
          for (int c = 0; c < 6; ++c) acc[r][c] = fmaf(qv[r], kv[c], acc[r][c]);
      }
      const float wj = (float)jj, wnj = (float)(16 - jj);
      float rs[3] = {0.f, 0.f, 0.f};
      #pragma unroll
      for (int r = 0; r < 3; ++r)
        #pragma unroll
        for (int c = 0; c < 6; ++c) {
          float w = ((tm + c) & 1) ? wj : wnj;
          float p = w * expf(acc[r][c] * SCALE_ATTN);
          su.a.Ss[(tl + r) * 97 + tm + c] = p;
          rs[r] += p;
        }
      #pragma unroll
      for (int r = 0; r < 3; ++r) {
        rs[r] += __shfl_xor(rs[r], 1); rs[r] += __shfl_xor(rs[r], 2);
        rs[r] += __shfl_xor(rs[r], 4); rs[r] += __shfl_xor(rs[r], 8);
      }
      if ((t & 15) == 0) {
        su.a.rinv[tl + 0] = 1.f / rs[0];
        su.a.rinv[tl + 1] = 1.f / rs[1];
        su.a.rinv[tl + 2] = 1.f / rs[2];
      }
    }
    __syncthreads();

    if (t < 192) {
      const int l0 = (t >> 3) * 2, d0 = (t & 7) * 4;
      float a0x=0.f,a0y=0.f,a0z=0.f,a0w=0.f, a1x=0.f,a1y=0.f,a1z=0.f,a1w=0.f;
      for (int m = 0; m < 96; ++m) {
        float p0 = su.a.Ss[l0 * 97 + m], p1 = su.a.Ss[(l0 + 1) * 97 + m];
        float4 v = *(const float4*)&su.a.Va[m * 36 + d0];
        a0x = fmaf(p0, v.x, a0x); a0y = fmaf(p0, v.y, a0y);
        a0z = fmaf(p0, v.z, a0z); a0w = fmaf(p0, v.w, a0w);
        a1x = fmaf(p1, v.x, a1x); a1y = fmaf(p1, v.y, a1y);
        a1z = fmaf(p1, v.z, a1z); a1w = fmaf(p1, v.w, a1w);
      }
      const float s0 = su.a.rinv[l0], s1 = su.a.rinv[l0 + 1];
      float* ao = ws + OFF_AOA + (size_t)(j1 * 96 + rb * 48 + l0) * 128 + h * 32 + d0;
      float4 o0; o0.x = a0x * s0; o0.y = a0y * s0; o0.z = a0z * s0; o0.w = a0w * s0;
      float4 o1; o1.x = a1x * s1; o1.y = a1y * s1; o1.z = a1z * s1; o1.w = a1w * s1;
      *(float4*)ao = o0;
      *(float4*)(ao + 128) = o1;
    }
  }
}

// ================================================================
// K7ab (r25 exact): merged epilogue — r15 dot structure + k8 atomic fold,
// float4-vectorized staging.
// ================================================================
__global__ __launch_bounds__(256) void k7ab_epi(
    const float* __restrict__ mow, const float* __restrict__ mob,
    const float* __restrict__ roww, const float* __restrict__ robb,
    const float* __restrict__ qw,  const float* __restrict__ qb,
    float* __restrict__ ws, float* __restrict__ out)
{
  __shared__ float rows_in[8][132];
  __shared__ float res[8][132];
  __shared__ float t1s[8][132];
  __shared__ float qpart[8][4];
  const int t  = threadIdx.x;
  const int r0 = blockIdx.x * 8;

  { // staging: 8 rows x 128 cols = 256 float4, one per thread
    int ri = t >> 5, c4 = (t & 31) * 4;
    int r = r0 + ri;
    float4 aoval, x1v;
    if (r < 768) {
      float4 n0 = *(const float4*)&ws[OFF_AOP + 0*98304 + (size_t)r*128 + c4];
      float4 n1 = *(const float4*)&ws[OFF_AOP + 1*98304 + (size_t)r*128 + c4];
      float4 n2 = *(const float4*)&ws[OFF_AOP + 2*98304 + (size_t)r*128 + c4];
      float4 n3 = *(const float4*)&ws[OFF_AOP + 3*98304 + (size_t)r*128 + c4];
      int hh = c4 >> 5;
      float den = ws[OFF_DEN + 0*3072 + r*4 + hh] + ws[OFF_DEN + 1*3072 + r*4 + hh]
                + ws[OFF_DEN + 2*3072 + r*4 + hh] + ws[OFF_DEN + 3*3072 + r*4 + hh];
      float rinv = 1.f / den;
      aoval.x = ((n0.x + n1.x) + (n2.x + n3.x)) * rinv;
      aoval.y = ((n0.y + n1.y) + (n2.y + n3.y)) * rinv;
      aoval.z = ((n0.z + n1.z) + (n2.z + n3.z)) * rinv;
      aoval.w = ((n0.w + n1.w) + (n2.w + n3.w)) * rinv;
      x1v = *(const float4*)&ws[OFF_XE + (size_t)r*128 + c4];
    } else {
      int rr = r - 768;
      aoval = *(const float4*)&ws[OFF_AOA + (size_t)rr*128 + c4];
      int jx = rr / 96, l96 = rr % 96;
      int b = l96 >> 1, sa = l96 & 1;
      int ag = sa ? (jx + 1) : jx;
      x1v = *(const float4*)&ws[OFF_XA + (size_t)(b*16 + ag)*128 + c4];
    }
    *(float4*)&rows_in[ri][c4] = aoval;
    *(float4*)&res[ri][c4] = x1v;
  }

  const int c = (t & 31) | ((t >> 6) << 5);
  const int h = (t >> 5) & 1;
  __syncthreads();

  { // t1 phase (runtime-looped chunks)
    float accs[8] = {0.f,0.f,0.f,0.f,0.f,0.f,0.f,0.f};
    const float* wb = mow + c * 128 + h * 64;
    #pragma unroll 1
    for (int ch = 0; ch < 2; ++ch) {
      const float4* wp = (const float4*)(wb + ch * 32);
      float4 wf[8];
      #pragma unroll
      for (int i = 0; i < 8; ++i) wf[i] = wp[i];
      #pragma unroll
      for (int ri = 0; ri < 8; ++ri) {
        const float* xr = &rows_in[ri][h * 64 + ch * 32];
        float ax = 0.f, ay = 0.f, az = 0.f, aw = 0.f;
        #pragma unroll
        for (int i = 0; i < 8; ++i) {
          float4 x = *(const float4*)&xr[i * 4];
          ax = fmaf(x.x, wf[i].x, ax); ay = fmaf(x.y, wf[i].y, ay);
          az = fmaf(x.z, wf[i].z, az); aw = fmaf(x.w, wf[i].w, aw);
        }
        accs[ri] += (ax + ay) + (az + aw);
      }
    }
    const float bias = mob[c];
    #pragma unroll
    for (int ri = 0; ri < 8; ++ri) {
      float acc = accs[ri];
      acc += __shfl_xor(acc, 32);
      if (h == 0) t1s[ri][c] = acc + bias + res[ri][c];
    }
  }
  __syncthreads();

  { // ctx + qv phase
    float accs[8] = {0.f,0.f,0.f,0.f,0.f,0.f,0.f,0.f};
    const float* wb = roww + c * 128 + h * 64;
    #pragma unroll 1
    for (int ch = 0; ch < 2; ++ch) {
      const float4* wp = (const float4*)(wb + ch * 32);
      float4 wf[8];
      #pragma unroll
      for (int i = 0; i < 8; ++i) wf[i] = wp[i];
      #pragma unroll
      for (int ri = 0; ri < 8; ++ri) {
        const float* xr = &t1s[ri][h * 64 + ch * 32];
        float ax = 0.f, ay = 0.f, az = 0.f, aw = 0.f;
        #pragma unroll
        for (int i = 0; i < 8; ++i) {
          float4 x = *(const float4*)&xr[i * 4];
          ax = fmaf(x.x, wf[i].x, ax); ay = fmaf(x.y, wf[i].y, ay);
          az = fmaf(x.z, wf[i].z, az); aw = fmaf(x.w, wf[i].w, aw);
        }
        accs[ri] += (ax + ay) + (az + aw);
      }
    }
    const float bias = robb[c];
    const float qwc  = qw[c];
    #pragma unroll
    for (int ri = 0; ri < 8; ++ri) {
      float acc = accs[ri];
      acc += __shfl_xor(acc, 32);
      float ctx = fmaxf(acc + bias, 0.f);
      float p = (h == 0) ? qwc * ctx : 0.f;
      p += __shfl_xor(p, 1);  p += __shfl_xor(p, 2);  p += __shfl_xor(p, 4);
      p += __shfl_xor(p, 8);  p += __shfl_xor(p, 16); p += __shfl_xor(p, 32);
      if ((t & 63) == 0) qpart[ri][t >> 6] = p;
    }
  }
  __syncthreads();

  if (t < 8) {
    float qv = (qpart[t][0] + qpart[t][1]) + (qpart[t][2] + qpart[t][3]) + qb[0];
    int r = r0 + t;
    if (r < 768) {
      atomicAdd(&out[OUT_QV + r], qv);
    } else {
      int rr = r - 768;
      int jx = rr / 96, l96 = rr % 96;
      int b = l96 >> 1, sa = l96 & 1;
      int jj = jx + 1;
      // s==0 row feeds i >= jj ; s==1 row feeds i < jj
      int ibeg = sa ? 0 : jj;
      int iend = sa ? jj : 16;
      for (int i = ibeg; i < iend; ++i)
        atomicAdd(&out[OUT_QV + b * 16 + i], qv);
    }
  }
}

// ================================================================
extern "C" void kernel_launch(void* const* d_in, const int* in_sizes, int n_in,
                              void* d_out, int out_size, void* d_ws, size_t ws_size,
                              hipStream_t stream)
{
  (void)in_sizes; (void)n_in; (void)out_size;
  if (ws_size < (size_t)WS_FLOATS * 4) return;

  const float* obs = (const float*)d_in[0];
  const float* aw1 = (const float*)d_in[1];
  const float* ab1 = (const float*)d_in[2];
  const float* aw2 = (const float*)d_in[3];
  const float* ab2 = (const float*)d_in[4];
  const float* aw3 = (const float*)d_in[5];
  const float* ab3 = (const float*)d_in[6];
  const float* eow = (const float*)d_in[7];
  const float* eob = (const float*)d_in[8];
  const float* eaw = (const float*)d_in[9];
  const float* eab = (const float*)d_in[10];
  const float* riw = (const float*)d_in[11];
  const float* rib = (const float*)d_in[12];
  const float* roww= (const float*)d_in[13];
  const float* robb= (const float*)d_in[14];
  const float* miw = (const float*)d_in[15];
  const float* mib = (const float*)d_in[16];
  const float* mow = (const float*)d_in[17];
  const float* mob = (const float*)d_in[18];
  const float* qw  = (const float*)d_in[19];
  const float* qb  = (const float*)d_in[20];

  float* out = (float*)d_out;
  float* ws  = (float*)d_ws;

  k12ws_front<<<dim3(384), dim3(512), 0, stream>>>(obs, aw1, ab1, aw2, ab2, aw3, ab3,
                                                   eow, eob, eaw, eab, riw, rib, miw, mib,
                                                   out, ws);
  k356_attn<<<dim3(888), dim3(256), 0, stream>>>(ws);
  k7ab_epi<<<dim3(276), dim3(256), 0, stream>>>(mow, mob, roww, robb, qw, qb, ws, out);
}